// Round 9
// baseline (314.360 us; speedup 1.0000x reference)
//
#include <hip/hip_runtime.h>
#include <hip/hip_bf16.h>
#include <math.h>

// Problem constants: S=4, B=1, C=128, h=w=d=10 -> N=1000, L=4000, nL=2, H=8, Dh=16
#define LL 4000
#define CC 128
#define NN 1000
#define NLAYER 2
#define KSPLIT 4                        // == S; split-K aligned to sequences
#define SCLOG2 0.36067376022224085f    // 0.25 * log2(e), folded into Q
#define ST 128                         // keys per supertile
#define KROW 18                        // padded LDS row (shorts), K tile [128][KROW]
#define VROW 130                       // padded LDS row (shorts), V^T tile [16][VROW]

typedef __attribute__((ext_vector_type(4))) short bf16x4;
typedef __attribute__((ext_vector_type(8))) short short8;
typedef __attribute__((ext_vector_type(4))) float f32x4;
typedef __attribute__((ext_vector_type(2))) unsigned int u32x2;

__device__ __forceinline__ short bf16rne(float f) {
    return __builtin_bit_cast(short, __float2bfloat16(f));
}

// pack 4 f32 -> 4 bf16 (truncate) via 2x v_perm_b32
__device__ __forceinline__ bf16x4 pack4(const float* p) {
    unsigned w01 = __builtin_amdgcn_perm(__builtin_bit_cast(unsigned, p[1]),
                                         __builtin_bit_cast(unsigned, p[0]),
                                         0x07060302u);
    unsigned w23 = __builtin_amdgcn_perm(__builtin_bit_cast(unsigned, p[3]),
                                         __builtin_bit_cast(unsigned, p[2]),
                                         0x07060302u);
    u32x2 w = {w01, w23};
    return __builtin_bit_cast(bf16x4, w);
}

// ---------------------------------------------------------------------------
// tokenize: z[S,1,C,N] + seq_embed[S,C] -> tok[L,C] (f32) + tokb (bf16)
__global__ void tokenize_kernel(const float* __restrict__ z,
                                const float* __restrict__ se,
                                float* __restrict__ tok,
                                short* __restrict__ tokb) {
    int idx = blockIdx.x * blockDim.x + threadIdx.x;
    if (idx >= LL * CC) return;
    int c = idx & (CC - 1);
    int t = idx >> 7;
    int s = t / NN;
    int n = t - s * NN;
    float v = z[(s * CC + c) * NN + n] + se[s * CC + c];
    tok[idx] = v;
    tokb[idx] = bf16rne(v);
}

// detokenize: tok[L,C] -> out[(s*C+c)*N + n]
__global__ void detok_kernel(const float* __restrict__ tok,
                             float* __restrict__ out) {
    int idx = blockIdx.x * blockDim.x + threadIdx.x;
    if (idx >= LL * CC) return;
    int n = idx % NN;
    int sc = idx / NN;
    int c = sc & (CC - 1);
    int s = sc >> 7;
    out[idx] = tok[(s * NN + n) * CC + c];
}

// kbw[l*KSPLIT+z] = r[z]^beta[l]  (per-sequence softmax weight; row term of
// log R is softmax-invariant, clamp inactive since r>=0.1)
__global__ void kbw_kernel(const float* __restrict__ r,
                           const float* __restrict__ beta,
                           float* __restrict__ kbw) {
    int idx = threadIdx.x;
    if (idx >= NLAYER * KSPLIT) return;
    int l = idx / KSPLIT;
    int z = idx - l * KSPLIT;
    kbw[idx] = exp2f(beta[l] * __log2f(r[z]));
}

// ---------------------------------------------------------------------------
// weight prep: bf16 + transpose -> Wt[N][K]
__global__ void prep_weights(const float* __restrict__ Wq, const float* __restrict__ Wk,
                             const float* __restrict__ Wv, const float* __restrict__ Wp,
                             const float* __restrict__ w1, const float* __restrict__ w2,
                             short* __restrict__ wt8, short* __restrict__ w1t,
                             short* __restrict__ w2t) {
    int idx = blockIdx.x * blockDim.x + threadIdx.x;
    if (idx < 8 * 16384) {
        int m = idx >> 14, i = idx & 16383;
        int n = i >> 7, k = i & 127;
        const float* src = (m < 2) ? Wq + (size_t)m * 16384
                         : (m < 4) ? Wk + (size_t)(m - 2) * 16384
                         : (m < 6) ? Wv + (size_t)(m - 4) * 16384
                                   : Wp + (size_t)(m - 6) * 16384;
        wt8[idx] = bf16rne(src[k * 128 + n]);
    } else if (idx < 8 * 16384 + 65536) {
        int i = idx - 8 * 16384;
        int n = i >> 7, k = i & 127;
        w1t[i] = bf16rne(w1[(size_t)k * 512 + n]);
    } else if (idx < 8 * 16384 + 2 * 65536) {
        int i = idx - 8 * 16384 - 65536;
        int n = i >> 9, k = i & 511;
        w2t[i] = bf16rne(w2[(size_t)k * 128 + n]);
    }
}

// ---------------------------------------------------------------------------
// MFMA GEMM body: out[M,N] = act(A[M,K] @ Wt[N,K]^T + bias)
// flags: 1 = bf16 out, 2 = exact GELU, 4 = bf16 transposed out [N][M],
//        8 = *SCLOG2, 16 = bf16 head-major out [N/16][M][16]
__device__ __forceinline__ void gemm_body(
        const short* __restrict__ A, const short* __restrict__ Wt,
        const float* __restrict__ bias, void* __restrict__ outp,
        int M, int K, int N, int flags, int row0, int col0) {
    __shared__ short Al[16][136];
    __shared__ short Wl[128][136];
    const int tid = threadIdx.x;
    const int lane = tid & 63;
    const int w = tid >> 6;
    const int lq = lane & 15, g = lane >> 4;

    f32x4 acc[2] = {{0.f,0.f,0.f,0.f},{0.f,0.f,0.f,0.f}};

    for (int kc = 0; kc < K; kc += 128) {
        {
            int r = tid >> 4, c = (tid & 15) * 8;
            *(short8*)&Al[r][c] = *(const short8*)(A + (size_t)(row0 + r) * K + kc + c);
        }
        {
            int c = (tid & 15) * 8;
            int nb = tid >> 4;
            #pragma unroll
            for (int i = 0; i < 8; ++i) {
                int n = nb + i * 16;
                *(short8*)&Wl[n][c] = *(const short8*)(Wt + (size_t)(col0 + n) * K + kc + c);
            }
        }
        __syncthreads();
        bf16x4 af[8];
        #pragma unroll
        for (int ks = 0; ks < 8; ++ks)
            af[ks] = *(const bf16x4*)&Al[lq][ks * 16 + g * 4];
        #pragma unroll
        for (int ct = 0; ct < 2; ++ct) {
            int n = (w * 2 + ct) * 16 + lq;
            #pragma unroll
            for (int ks = 0; ks < 8; ++ks) {
                bf16x4 bfr = *(const bf16x4*)&Wl[n][ks * 16 + g * 4];
                acc[ct] = __builtin_amdgcn_mfma_f32_16x16x16bf16_1k(af[ks], bfr, acc[ct], 0, 0, 0);
            }
        }
        __syncthreads();
    }
    #pragma unroll
    for (int ct = 0; ct < 2; ++ct) {
        int col = col0 + (w * 2 + ct) * 16 + lq;
        float bv = bias ? bias[col] : 0.f;
        float v[4];
        #pragma unroll
        for (int r = 0; r < 4; ++r) {
            v[r] = acc[ct][r] + bv;
            if (flags & 2) v[r] = 0.5f * v[r] * (1.f + erff(v[r] * 0.70710678118654752f));
            if (flags & 8) v[r] *= SCLOG2;
        }
        if (flags & 4) {
            bf16x4 res = {bf16rne(v[0]), bf16rne(v[1]), bf16rne(v[2]), bf16rne(v[3])};
            *(bf16x4*)((short*)outp + (size_t)col * M + row0 + g * 4) = res;
        } else if (flags & 16) {   // head-major [H][M][16]
            #pragma unroll
            for (int r = 0; r < 4; ++r)
                ((short*)outp)[((size_t)(col >> 4) * M + (row0 + g * 4 + r)) * 16 + (col & 15)] = bf16rne(v[r]);
        } else if (flags & 1) {
            #pragma unroll
            for (int r = 0; r < 4; ++r)
                ((short*)outp)[(size_t)(row0 + g * 4 + r) * N + col] = bf16rne(v[r]);
        } else {
            #pragma unroll
            for (int r = 0; r < 4; ++r)
                ((float*)outp)[(size_t)(row0 + g * 4 + r) * N + col] = v[r];
        }
    }
}

__global__ __launch_bounds__(256) void mfma_gemm(
        const short* __restrict__ A, const short* __restrict__ Wt,
        const float* __restrict__ bias, void* __restrict__ outp,
        int M, int K, int N, int flags) {
    gemm_body(A, Wt, bias, outp, M, K, N, flags,
              blockIdx.x * 16, blockIdx.y * 128);
}

// fused QKV: z=0 Q (bf16, *SCLOG2), z=1 K (head-major [H][L][16]), z=2 V^T [C][L]
__global__ __launch_bounds__(256) void mfma_gemm3(
        const short* __restrict__ A,
        const short* __restrict__ W0, const short* __restrict__ W1,
        const short* __restrict__ W2,
        short* __restrict__ o0, short* __restrict__ o1, short* __restrict__ o2,
        int M, int K, int N) {
    const short* Wt = (blockIdx.z == 0) ? W0 : (blockIdx.z == 1) ? W1 : W2;
    short* o = (blockIdx.z == 0) ? o0 : (blockIdx.z == 1) ? o1 : o2;
    int flags = (blockIdx.z == 0) ? (1 | 8) : (blockIdx.z == 1) ? 16 : 4;
    gemm_body(A, Wt, nullptr, o, M, K, N, flags, blockIdx.x * 16, 0);
}

// ---------------------------------------------------------------------------
// Fused MFMA GEMM (N=128) + residual add + LayerNorm. Block = 4 waves =
// 16 full rows; stats via intra-wave shuffles + tiny LDS exchange.
__global__ __launch_bounds__(256) void mfma_gemm_ln(
        const short* __restrict__ A, const short* __restrict__ Wt,
        const float* __restrict__ bias, const float* __restrict__ resid,
        const float* __restrict__ gam, const float* __restrict__ bet,
        float* __restrict__ outf, short* __restrict__ outb,
        int M, int K) {
    __shared__ short Al[16][136];
    __shared__ short Wl[128][136];
    __shared__ float sL[4][4][4], s2L[4][4][4];
    const int tid = threadIdx.x;
    const int lane = tid & 63;
    const int w = tid >> 6;
    const int lq = lane & 15, g = lane >> 4;
    const int row0 = blockIdx.x * 16;

    f32x4 acc[2] = {{0.f,0.f,0.f,0.f},{0.f,0.f,0.f,0.f}};

    for (int kc = 0; kc < K; kc += 128) {
        {
            int r = tid >> 4, c = (tid & 15) * 8;
            *(short8*)&Al[r][c] = *(const short8*)(A + (size_t)(row0 + r) * K + kc + c);
        }
        {
            int c = (tid & 15) * 8;
            int nb = tid >> 4;
            #pragma unroll
            for (int i = 0; i < 8; ++i) {
                int n = nb + i * 16;
                *(short8*)&Wl[n][c] = *(const short8*)(Wt + (size_t)n * K + kc + c);
            }
        }
        __syncthreads();
        bf16x4 af[8];
        #pragma unroll
        for (int ks = 0; ks < 8; ++ks)
            af[ks] = *(const bf16x4*)&Al[lq][ks * 16 + g * 4];
        #pragma unroll
        for (int ct = 0; ct < 2; ++ct) {
            int n = (w * 2 + ct) * 16 + lq;
            #pragma unroll
            for (int ks = 0; ks < 8; ++ks) {
                bf16x4 bfr = *(const bf16x4*)&Wl[n][ks * 16 + g * 4];
                acc[ct] = __builtin_amdgcn_mfma_f32_16x16x16bf16_1k(af[ks], bfr, acc[ct], 0, 0, 0);
            }
        }
        __syncthreads();
    }

    float v[2][4];
    int cols[2] = {(w * 2) * 16 + lq, (w * 2 + 1) * 16 + lq};
    #pragma unroll
    for (int ct = 0; ct < 2; ++ct) {
        float bv = bias ? bias[cols[ct]] : 0.f;
        #pragma unroll
        for (int r = 0; r < 4; ++r)
            v[ct][r] = acc[ct][r] + bv +
                       resid[(size_t)(row0 + g * 4 + r) * CC + cols[ct]];
    }
    float sr[4], s2r[4];
    #pragma unroll
    for (int r = 0; r < 4; ++r) {
        sr[r]  = v[0][r] + v[1][r];
        s2r[r] = v[0][r] * v[0][r] + v[1][r] * v[1][r];
    }
    #pragma unroll
    for (int off = 1; off < 16; off <<= 1) {
        #pragma unroll
        for (int r = 0; r < 4; ++r) {
            sr[r]  += __shfl_xor(sr[r],  off);
            s2r[r] += __shfl_xor(s2r[r], off);
        }
    }
    if (lq == 0) {
        #pragma unroll
        for (int r = 0; r < 4; ++r) { sL[w][g][r] = sr[r]; s2L[w][g][r] = s2r[r]; }
    }
    __syncthreads();
    #pragma unroll
    for (int r = 0; r < 4; ++r) {
        float s = 0.f, s2 = 0.f;
        #pragma unroll
        for (int ww = 0; ww < 4; ++ww) { s += sL[ww][g][r]; s2 += s2L[ww][g][r]; }
        float mu = s * (1.f / CC);
        float var = s2 * (1.f / CC) - mu * mu;
        float rstd = rsqrtf(var + 1e-5f);
        size_t rowoff = (size_t)(row0 + g * 4 + r) * CC;
        #pragma unroll
        for (int ct = 0; ct < 2; ++ct) {
            float y = (v[ct][r] - mu) * rstd * gam[cols[ct]] + bet[cols[ct]];
            outf[rowoff + cols[ct]] = y;
            outb[rowoff + cols[ct]] = bf16rne(y);
        }
    }
}

// ---------------------------------------------------------------------------
// MFMA flash attention, fixed-shift softmax, sequence-aligned split-K.
// Block = 256 thr = 4 waves = 4 q-tiles sharing (head, z). 128-key supertiles
// staged via ONE short8 (16B) K-load + ONE V-load per thread, double-buffered,
// 1 barrier per supertile (8 total). z-range padded to 1024 keys: last
// supertile runs subs 0..5 full, sub 6 g<2-masked, sub 7 skipped.
__global__ __launch_bounds__(256, 4) void attn_mfma_kernel(
        const short* __restrict__ Qb, const short* __restrict__ Kh,
        const short* __restrict__ Vt, const float* __restrict__ kbw,
        float* __restrict__ po, float* __restrict__ pl) {
    __shared__ short Kl[2][128 * KROW];
    __shared__ short Vl[2][16 * VROW];
    const int tid  = threadIdx.x;
    const int lane = tid & 63;
    const int w    = tid >> 6;
    const int lq = lane & 15;
    const int g  = lane >> 4;
    const int h  = blockIdx.y;
    const int z  = blockIdx.z;
    const int qtile = blockIdx.x * 4 + w;
    const bool qv = qtile < LL / 16;
    const int q0 = qtile * 16;
    const int hd0 = h * 16;
    const int kbase = z * NN;

    bf16x4 qf = {0, 0, 0, 0};
    if (qv) qf = *(const bf16x4*)(Qb + (size_t)(q0 + lq) * CC + hd0 + 4 * g);

    // staging pointers: thread loads 16B of K (row tid>>1, half tid&1) and
    // 16B of V^T (d-row tid>>4, key-seg tid&15)
    const short* kgp = Kh + ((size_t)h * LL + kbase + (tid >> 1)) * 16 + (tid & 1) * 8;
    const short* vgp = Vt + (size_t)(hd0 + (tid >> 4)) * LL + kbase + (tid & 15) * 8;
    short* kwp = &Kl[0][0] + (tid >> 1) * KROW + (tid & 1) * 8;
    short* vwp = &Vl[0][0] + (tid >> 4) * VROW + (tid & 15) * 8;

    f32x4 o = {0.f, 0.f, 0.f, 0.f};
    float psum = 0.f;

    {   // prologue: stage supertile 0 into buf 0
        short8 kd = *(const short8*)kgp;
        short8 vd = *(const short8*)vgp;
        *(short8*)kwp = kd;
        *(short8*)vwp = vd;
    }
    __syncthreads();

    #define SUBFULL(kb, vb, u)                                                 \
        {   bf16x4 Ku = *(const bf16x4*)((kb) + ((u) * 16 + lq) * KROW + 4 * g); \
            const f32x4 zz = {0.f, 0.f, 0.f, 0.f};                             \
            f32x4 su = __builtin_amdgcn_mfma_f32_16x16x16bf16_1k(Ku, qf, zz, 0, 0, 0); \
            float p[4];                                                        \
            _Pragma("unroll")                                                  \
            for (int r = 0; r < 4; ++r) {                                      \
                p[r] = __builtin_amdgcn_exp2f(su[r]);                          \
                psum += p[r];                                                  \
            }                                                                  \
            bf16x4 ptu = pack4(p);                                             \
            bf16x4 Vu = *(const bf16x4*)((vb) + lq * VROW + (u) * 16 + 4 * g); \
            o = __builtin_amdgcn_mfma_f32_16x16x16bf16_1k(Vu, ptu, o, 0, 0, 0); }

    for (int st = 0; st < 7; ++st) {
        // prefetch supertile st+1 (T14: issue early, write late)
        short8 kd = *(const short8*)(kgp + (size_t)(st + 1) * (ST * 16));
        short8 vd = *(const short8*)(vgp + (st + 1) * ST);
        const short* kb = &Kl[st & 1][0];
        const short* vb = &Vl[st & 1][0];
        #pragma unroll
        for (int u = 0; u < 8; ++u) SUBFULL(kb, vb, u)
        *(short8*)(kwp + ((st + 1) & 1) * (128 * KROW)) = kd;
        *(short8*)(vwp + ((st + 1) & 1) * (16 * VROW)) = vd;
        __syncthreads();
    }
    {   // supertile 7 (keys 896..1023 local): subs 0..5 full; sub 6 masked
        const short* kb = &Kl[1][0];
        const short* vb = &Vl[1][0];
        #pragma unroll
        for (int u = 0; u < 6; ++u) SUBFULL(kb, vb, u)
        {   // sub 6: keys 992..1007; valid iff 4g+r < 8 -> g < 2
            bf16x4 Ku = *(const bf16x4*)(kb + (6 * 16 + lq) * KROW + 4 * g);
            const f32x4 zz = {0.f, 0.f, 0.f, 0.f};
            f32x4 su = __builtin_amdgcn_mfma_f32_16x16x16bf16_1k(Ku, qf, zz, 0, 0, 0);
            float p[4];
            #pragma unroll
            for (int r = 0; r < 4; ++r) {
                p[r] = (g < 2) ? __builtin_amdgcn_exp2f(su[r]) : 0.f;
                psum += p[r];
            }
            bf16x4 ptu = pack4(p);
            bf16x4 Vu = *(const bf16x4*)(vb + lq * VROW + 6 * 16 + 4 * g);
            if (g >= 2) Vu = (bf16x4){0, 0, 0, 0};
            o = __builtin_amdgcn_mfma_f32_16x16x16bf16_1k(Vu, ptu, o, 0, 0, 0);
        }
        // sub 7 (keys 1008..1023): all invalid, skipped
    }
    #undef SUBFULL

    const float wz = kbw[z];
    psum += __shfl_xor(psum, 16);
    psum += __shfl_xor(psum, 32);
    if (qv) {
        f32x4 ow = {o[0] * wz, o[1] * wz, o[2] * wz, o[3] * wz};
        *(f32x4*)(po + (size_t)z * LL * CC + (size_t)(q0 + lq) * CC + hd0 + 4 * g) = ow;
        if (g == 0) pl[(z * 8 + h) * LL + q0 + lq] = psum * wz;
    }
}

// combine: attb[q][c] = bf16( sum_z po / sum_z pl )
__global__ void attn_combine(const float* __restrict__ po,
                             const float* __restrict__ pl,
                             short* __restrict__ attb) {
    int i = blockIdx.x * blockDim.x + threadIdx.x;
    if (i >= LL * CC / 4) return;
    int q  = i >> 5;
    int c0 = (i & 31) * 4;
    int h  = c0 >> 4;
    size_t off = (size_t)q * CC + c0;
    f32x4 o = {0.f, 0.f, 0.f, 0.f};
    float l = 0.f;
    #pragma unroll
    for (int zz = 0; zz < KSPLIT; ++zz) {
        f32x4 t = *(const f32x4*)(po + (size_t)zz * LL * CC + off);
        o[0] += t[0]; o[1] += t[1]; o[2] += t[2]; o[3] += t[3];
        l += pl[(zz * 8 + h) * LL + q];
    }
    float inv = 1.f / l;
    bf16x4 res = {bf16rne(o[0] * inv), bf16rne(o[1] * inv),
                  bf16rne(o[2] * inv), bf16rne(o[3] * inv)};
    *(bf16x4*)(attb + off) = res;
}

// ---------------------------------------------------------------------------
extern "C" void kernel_launch(void* const* d_in, const int* in_sizes, int n_in,
                              void* d_out, int out_size, void* d_ws, size_t ws_size,
                              hipStream_t stream) {
    const float* z    = (const float*)d_in[0];
    const float* r    = (const float*)d_in[1];
    const float* se   = (const float*)d_in[2];
    const float* Wq   = (const float*)d_in[3];
    const float* Wk   = (const float*)d_in[4];
    const float* Wv   = (const float*)d_in[5];
    const float* Wp   = (const float*)d_in[6];
    const float* beta = (const float*)d_in[7];
    const float* ln1g = (const float*)d_in[8];
    const float* ln1b = (const float*)d_in[9];
    const float* w1   = (const float*)d_in[10];
    const float* b1   = (const float*)d_in[11];
    const float* w2   = (const float*)d_in[12];
    const float* b2   = (const float*)d_in[13];
    const float* ln2g = (const float*)d_in[14];
    const float* ln2b = (const float*)d_in[15];
    float* out = (float*)d_out;

    float* ws   = (float*)d_ws;
    float* tok  = ws;                               // 512000 f
    float* kbw  = tok + LL * CC;                    // 8 f (16B aligned)
    float* pl   = kbw + 8;                          // KSPLIT*8*LL = 128000 f
    float* po   = pl + KSPLIT * 8 * LL;             // KSPLIT*LL*CC f = 8 MB
    short* hdn  = (short*)po;                       // aliased: FFN phase only
    short* tokb = (short*)(po + (size_t)KSPLIT * LL * CC);
    short* attb = tokb + LL * CC;
    short* Qb   = attb + LL * CC;
    short* Kh   = Qb   + LL * CC;                   // head-major [H][L][16] + slack
    short* Vt   = Kh   + LL * CC + 1024;            // transposed [C][L] + slack
    short* wt8  = Vt   + LL * CC + 1024;
    short* w1t  = wt8  + 8 * 16384;
    short* w2t  = w1t  + 65536;

    prep_weights<<<1024, 256, 0, stream>>>(Wq, Wk, Wv, Wp, w1, w2, wt8, w1t, w2t);
    tokenize_kernel<<<2000, 256, 0, stream>>>(z, se, tok, tokb);
    kbw_kernel<<<1, 64, 0, stream>>>(r, beta, kbw);

    for (int l = 0; l < NLAYER; ++l) {
        const short* wqt = wt8 + (size_t)(0 * 2 + l) * 16384;
        const short* wkt = wt8 + (size_t)(1 * 2 + l) * 16384;
        const short* wvt = wt8 + (size_t)(2 * 2 + l) * 16384;
        const short* wpt = wt8 + (size_t)(3 * 2 + l) * 16384;
        mfma_gemm3<<<dim3(LL / 16, 1, 3), 256, 0, stream>>>(
            tokb, wqt, wkt, wvt, Qb, Kh, Vt, LL, CC, CC);
        attn_mfma_kernel<<<dim3((LL / 16 + 3) / 4, 8, KSPLIT), 256, 0, stream>>>(
            Qb, Kh, Vt, kbw + l * KSPLIT, po, pl);
        attn_combine<<<(LL * CC / 4 + 255) / 256, 256, 0, stream>>>(po, pl, attb);
        mfma_gemm_ln<<<LL / 16, 256, 0, stream>>>(
            attb, wpt, nullptr, tok, ln1g + l * CC, ln1b + l * CC,
            tok, tokb, LL, CC);
    }

    mfma_gemm<<<dim3(LL / 16, 4), 256, 0, stream>>>(tokb, w1t, b1, hdn, LL, CC, 4 * CC, 1 | 2);
    mfma_gemm_ln<<<LL / 16, 256, 0, stream>>>(
        hdn, w2t, b2, tok, ln2g, ln2b, tok, tokb, LL, 4 * CC);

    detok_kernel<<<2000, 256, 0, stream>>>(tok, out);
}

// Round 10
// 115.248 us; speedup vs baseline: 2.7277x; 2.7277x over previous
//
#include <hip/hip_runtime.h>
#include <hip/hip_bf16.h>
#include <math.h>

// Problem constants: S=4, B=1, C=128, h=w=d=10 -> N=1000, L=4000, nL=2, H=8, Dh=16
#define LL 4000
#define CC 128
#define NN 1000
#define NLAYER 2
#define KSPLIT 4                        // == S; split-K aligned to sequences
#define SCLOG2 0.36067376022224085f    // 0.25 * log2(e), folded into Q
#define KROW 20                        // padded LDS row (shorts) for K tile [32][KROW]
#define VROW 36                        // padded LDS row (shorts) for V^T tile [16][VROW]

typedef __attribute__((ext_vector_type(4))) short bf16x4;
typedef __attribute__((ext_vector_type(8))) short short8;
typedef __attribute__((ext_vector_type(4))) float f32x4;
typedef __attribute__((ext_vector_type(2))) unsigned int u32x2;

__device__ __forceinline__ short bf16rne(float f) {
    return __builtin_bit_cast(short, __float2bfloat16(f));
}

// pack 4 f32 -> 4 bf16 (truncate) via 2x v_perm_b32
__device__ __forceinline__ bf16x4 pack4(const float* p) {
    unsigned w01 = __builtin_amdgcn_perm(__builtin_bit_cast(unsigned, p[1]),
                                         __builtin_bit_cast(unsigned, p[0]),
                                         0x07060302u);
    unsigned w23 = __builtin_amdgcn_perm(__builtin_bit_cast(unsigned, p[3]),
                                         __builtin_bit_cast(unsigned, p[2]),
                                         0x07060302u);
    u32x2 w = {w01, w23};
    return __builtin_bit_cast(bf16x4, w);
}

// ---------------------------------------------------------------------------
// tokenize: z[S,1,C,N] + seq_embed[S,C] -> tok[L,C] (f32) + tokb (bf16)
__global__ void tokenize_kernel(const float* __restrict__ z,
                                const float* __restrict__ se,
                                float* __restrict__ tok,
                                short* __restrict__ tokb) {
    int idx = blockIdx.x * blockDim.x + threadIdx.x;
    if (idx >= LL * CC) return;
    int c = idx & (CC - 1);
    int t = idx >> 7;
    int s = t / NN;
    int n = t - s * NN;
    float v = z[(s * CC + c) * NN + n] + se[s * CC + c];
    tok[idx] = v;
    tokb[idx] = bf16rne(v);
}

// detokenize: tok[L,C] -> out[(s*C+c)*N + n]
__global__ void detok_kernel(const float* __restrict__ tok,
                             float* __restrict__ out) {
    int idx = blockIdx.x * blockDim.x + threadIdx.x;
    if (idx >= LL * CC) return;
    int n = idx % NN;
    int sc = idx / NN;
    int c = sc & (CC - 1);
    int s = sc >> 7;
    out[idx] = tok[(s * NN + n) * CC + c];
}

// kbw[l*KSPLIT+z] = r[z]^beta[l]  (per-sequence softmax weight; row term of
// log R is softmax-invariant, clamp inactive since r>=0.1)
__global__ void kbw_kernel(const float* __restrict__ r,
                           const float* __restrict__ beta,
                           float* __restrict__ kbw) {
    int idx = threadIdx.x;
    if (idx >= NLAYER * KSPLIT) return;
    int l = idx / KSPLIT;
    int z = idx - l * KSPLIT;
    kbw[idx] = exp2f(beta[l] * __log2f(r[z]));
}

// ---------------------------------------------------------------------------
// weight prep: bf16 + transpose -> Wt[N][K]
__global__ void prep_weights(const float* __restrict__ Wq, const float* __restrict__ Wk,
                             const float* __restrict__ Wv, const float* __restrict__ Wp,
                             const float* __restrict__ w1, const float* __restrict__ w2,
                             short* __restrict__ wt8, short* __restrict__ w1t,
                             short* __restrict__ w2t) {
    int idx = blockIdx.x * blockDim.x + threadIdx.x;
    if (idx < 8 * 16384) {
        int m = idx >> 14, i = idx & 16383;
        int n = i >> 7, k = i & 127;
        const float* src = (m < 2) ? Wq + (size_t)m * 16384
                         : (m < 4) ? Wk + (size_t)(m - 2) * 16384
                         : (m < 6) ? Wv + (size_t)(m - 4) * 16384
                                   : Wp + (size_t)(m - 6) * 16384;
        wt8[idx] = bf16rne(src[k * 128 + n]);
    } else if (idx < 8 * 16384 + 65536) {
        int i = idx - 8 * 16384;
        int n = i >> 7, k = i & 127;
        w1t[i] = bf16rne(w1[(size_t)k * 512 + n]);
    } else if (idx < 8 * 16384 + 2 * 65536) {
        int i = idx - 8 * 16384 - 65536;
        int n = i >> 9, k = i & 511;
        w2t[i] = bf16rne(w2[(size_t)k * 128 + n]);
    }
}

// ---------------------------------------------------------------------------
// MFMA GEMM body: out[M,N] = act(A[M,K] @ Wt[N,K]^T + bias)
// flags: 1 = bf16 out, 2 = exact GELU, 4 = bf16 transposed out [N][M],
//        8 = *SCLOG2, 16 = bf16 head-major out [N/16][M][16]
__device__ __forceinline__ void gemm_body(
        const short* __restrict__ A, const short* __restrict__ Wt,
        const float* __restrict__ bias, void* __restrict__ outp,
        int M, int K, int N, int flags, int row0, int col0) {
    __shared__ short Al[16][136];
    __shared__ short Wl[128][136];
    const int tid = threadIdx.x;
    const int lane = tid & 63;
    const int w = tid >> 6;
    const int lq = lane & 15, g = lane >> 4;

    f32x4 acc[2] = {{0.f,0.f,0.f,0.f},{0.f,0.f,0.f,0.f}};

    for (int kc = 0; kc < K; kc += 128) {
        {
            int r = tid >> 4, c = (tid & 15) * 8;
            *(short8*)&Al[r][c] = *(const short8*)(A + (size_t)(row0 + r) * K + kc + c);
        }
        {
            int c = (tid & 15) * 8;
            int nb = tid >> 4;
            #pragma unroll
            for (int i = 0; i < 8; ++i) {
                int n = nb + i * 16;
                *(short8*)&Wl[n][c] = *(const short8*)(Wt + (size_t)(col0 + n) * K + kc + c);
            }
        }
        __syncthreads();
        bf16x4 af[8];
        #pragma unroll
        for (int ks = 0; ks < 8; ++ks)
            af[ks] = *(const bf16x4*)&Al[lq][ks * 16 + g * 4];
        #pragma unroll
        for (int ct = 0; ct < 2; ++ct) {
            int n = (w * 2 + ct) * 16 + lq;
            #pragma unroll
            for (int ks = 0; ks < 8; ++ks) {
                bf16x4 bfr = *(const bf16x4*)&Wl[n][ks * 16 + g * 4];
                acc[ct] = __builtin_amdgcn_mfma_f32_16x16x16bf16_1k(af[ks], bfr, acc[ct], 0, 0, 0);
            }
        }
        __syncthreads();
    }
    #pragma unroll
    for (int ct = 0; ct < 2; ++ct) {
        int col = col0 + (w * 2 + ct) * 16 + lq;
        float bv = bias ? bias[col] : 0.f;
        float v[4];
        #pragma unroll
        for (int r = 0; r < 4; ++r) {
            v[r] = acc[ct][r] + bv;
            if (flags & 2) v[r] = 0.5f * v[r] * (1.f + erff(v[r] * 0.70710678118654752f));
            if (flags & 8) v[r] *= SCLOG2;
        }
        if (flags & 4) {
            bf16x4 res = {bf16rne(v[0]), bf16rne(v[1]), bf16rne(v[2]), bf16rne(v[3])};
            *(bf16x4*)((short*)outp + (size_t)col * M + row0 + g * 4) = res;
        } else if (flags & 16) {   // head-major [H][M][16]
            #pragma unroll
            for (int r = 0; r < 4; ++r)
                ((short*)outp)[((size_t)(col >> 4) * M + (row0 + g * 4 + r)) * 16 + (col & 15)] = bf16rne(v[r]);
        } else if (flags & 1) {
            #pragma unroll
            for (int r = 0; r < 4; ++r)
                ((short*)outp)[(size_t)(row0 + g * 4 + r) * N + col] = bf16rne(v[r]);
        } else {
            #pragma unroll
            for (int r = 0; r < 4; ++r)
                ((float*)outp)[(size_t)(row0 + g * 4 + r) * N + col] = v[r];
        }
    }
}

__global__ __launch_bounds__(256) void mfma_gemm(
        const short* __restrict__ A, const short* __restrict__ Wt,
        const float* __restrict__ bias, void* __restrict__ outp,
        int M, int K, int N, int flags) {
    gemm_body(A, Wt, bias, outp, M, K, N, flags,
              blockIdx.x * 16, blockIdx.y * 128);
}

// fused QKV: z=0 Q (bf16, *SCLOG2), z=1 K (head-major [H][L][16]), z=2 V^T [C][L]
__global__ __launch_bounds__(256) void mfma_gemm3(
        const short* __restrict__ A,
        const short* __restrict__ W0, const short* __restrict__ W1,
        const short* __restrict__ W2,
        short* __restrict__ o0, short* __restrict__ o1, short* __restrict__ o2,
        int M, int K, int N) {
    const short* Wt = (blockIdx.z == 0) ? W0 : (blockIdx.z == 1) ? W1 : W2;
    short* o = (blockIdx.z == 0) ? o0 : (blockIdx.z == 1) ? o1 : o2;
    int flags = (blockIdx.z == 0) ? (1 | 8) : (blockIdx.z == 1) ? 16 : 4;
    gemm_body(A, Wt, nullptr, o, M, K, N, flags, blockIdx.x * 16, 0);
}

// ---------------------------------------------------------------------------
// Fused MFMA GEMM (N=128) + residual add + LayerNorm. Block = 4 waves =
// 16 full rows; stats via intra-wave shuffles + tiny LDS exchange.
__global__ __launch_bounds__(256) void mfma_gemm_ln(
        const short* __restrict__ A, const short* __restrict__ Wt,
        const float* __restrict__ bias, const float* __restrict__ resid,
        const float* __restrict__ gam, const float* __restrict__ bet,
        float* __restrict__ outf, short* __restrict__ outb,
        int M, int K) {
    __shared__ short Al[16][136];
    __shared__ short Wl[128][136];
    __shared__ float sL[4][4][4], s2L[4][4][4];
    const int tid = threadIdx.x;
    const int lane = tid & 63;
    const int w = tid >> 6;
    const int lq = lane & 15, g = lane >> 4;
    const int row0 = blockIdx.x * 16;

    f32x4 acc[2] = {{0.f,0.f,0.f,0.f},{0.f,0.f,0.f,0.f}};

    for (int kc = 0; kc < K; kc += 128) {
        {
            int r = tid >> 4, c = (tid & 15) * 8;
            *(short8*)&Al[r][c] = *(const short8*)(A + (size_t)(row0 + r) * K + kc + c);
        }
        {
            int c = (tid & 15) * 8;
            int nb = tid >> 4;
            #pragma unroll
            for (int i = 0; i < 8; ++i) {
                int n = nb + i * 16;
                *(short8*)&Wl[n][c] = *(const short8*)(Wt + (size_t)n * K + kc + c);
            }
        }
        __syncthreads();
        bf16x4 af[8];
        #pragma unroll
        for (int ks = 0; ks < 8; ++ks)
            af[ks] = *(const bf16x4*)&Al[lq][ks * 16 + g * 4];
        #pragma unroll
        for (int ct = 0; ct < 2; ++ct) {
            int n = (w * 2 + ct) * 16 + lq;
            #pragma unroll
            for (int ks = 0; ks < 8; ++ks) {
                bf16x4 bfr = *(const bf16x4*)&Wl[n][ks * 16 + g * 4];
                acc[ct] = __builtin_amdgcn_mfma_f32_16x16x16bf16_1k(af[ks], bfr, acc[ct], 0, 0, 0);
            }
        }
        __syncthreads();
    }

    float v[2][4];
    int cols[2] = {(w * 2) * 16 + lq, (w * 2 + 1) * 16 + lq};
    #pragma unroll
    for (int ct = 0; ct < 2; ++ct) {
        float bv = bias ? bias[cols[ct]] : 0.f;
        #pragma unroll
        for (int r = 0; r < 4; ++r)
            v[ct][r] = acc[ct][r] + bv +
                       resid[(size_t)(row0 + g * 4 + r) * CC + cols[ct]];
    }
    float sr[4], s2r[4];
    #pragma unroll
    for (int r = 0; r < 4; ++r) {
        sr[r]  = v[0][r] + v[1][r];
        s2r[r] = v[0][r] * v[0][r] + v[1][r] * v[1][r];
    }
    #pragma unroll
    for (int off = 1; off < 16; off <<= 1) {
        #pragma unroll
        for (int r = 0; r < 4; ++r) {
            sr[r]  += __shfl_xor(sr[r],  off);
            s2r[r] += __shfl_xor(s2r[r], off);
        }
    }
    if (lq == 0) {
        #pragma unroll
        for (int r = 0; r < 4; ++r) { sL[w][g][r] = sr[r]; s2L[w][g][r] = s2r[r]; }
    }
    __syncthreads();
    #pragma unroll
    for (int r = 0; r < 4; ++r) {
        float s = 0.f, s2 = 0.f;
        #pragma unroll
        for (int ww = 0; ww < 4; ++ww) { s += sL[ww][g][r]; s2 += s2L[ww][g][r]; }
        float mu = s * (1.f / CC);
        float var = s2 * (1.f / CC) - mu * mu;
        float rstd = rsqrtf(var + 1e-5f);
        size_t rowoff = (size_t)(row0 + g * 4 + r) * CC;
        #pragma unroll
        for (int ct = 0; ct < 2; ++ct) {
            float y = (v[ct][r] - mu) * rstd * gam[cols[ct]] + bet[cols[ct]];
            outf[rowoff + cols[ct]] = y;
            outb[rowoff + cols[ct]] = bf16rne(y);
        }
    }
}

// ---------------------------------------------------------------------------
// MFMA flash attention (r7-verbatim): fixed-shift softmax, sequence-aligned
// split-K, LDS-staged 32-key K/V tiles shared by 4 waves (4 q-tiles) per block.
// K staged from head-major Kh[H][L][16]; V^T staged from Vt[C][L]. Fragments
// via ds_read_b64 from padded LDS rows. Double-buffered, one barrier/tile,
// issue-early/write-late staging (T14).
__global__ __launch_bounds__(256) void attn_mfma_kernel(
        const short* __restrict__ Qb, const short* __restrict__ Kh,
        const short* __restrict__ Vt, const float* __restrict__ kbw,
        float* __restrict__ po, float* __restrict__ pl) {
    __shared__ short Kl[2][32][KROW];
    __shared__ short Vl[2][16][VROW];
    const int tid  = threadIdx.x;
    const int lane = tid & 63;
    const int wv   = tid >> 6;
    const int lq = lane & 15;
    const int g  = lane >> 4;
    const int h  = blockIdx.y;
    const int z  = blockIdx.z;
    const int qt = blockIdx.x * 4 + wv;
    const int q0 = qt * 16;
    const int hd0 = h * 16;
    const int kbase = z * NN;
    const bool qvalid = qt < LL / 16;

    bf16x4 qf = {0, 0, 0, 0};
    if (qvalid) qf = *(const bf16x4*)(Qb + (size_t)(q0 + lq) * CC + hd0 + 4 * g);

    // ones-row A fragment: A[0][k] = 1 -> D[0][q] = sum_k P[k][q]
    const short onev = (lq == 0) ? (short)0x3F80 : (short)0;
    const bf16x4 af1 = {onev, onev, onev, onev};

    // staging addresses (thread-flat across the block)
    const short* kgp = Kh + ((size_t)h * LL + kbase) * 16 + tid * 2;
    const short* vgp = Vt + (size_t)(hd0 + (tid >> 4)) * LL + kbase + (tid & 15) * 2;
    short* kwp = &Kl[0][0][0] + (tid >> 3) * KROW + (tid & 7) * 2;
    short* vwp = &Vl[0][0][0] + (tid >> 4) * VROW + (tid & 15) * 2;
    const int kbufstride = 32 * KROW;
    const int vbufstride = 16 * VROW;

    f32x4 o  = {0.f, 0.f, 0.f, 0.f};
    f32x4 ps = {0.f, 0.f, 0.f, 0.f};

    {   // prologue: stage tile 0 into buf 0
        unsigned kd = *(const unsigned*)kgp;
        unsigned vd = *(const unsigned*)vgp;
        *(unsigned*)kwp = kd;
        *(unsigned*)vwp = vd;
    }
    __syncthreads();

    for (int t = 0; t < 31; ++t) {
        // issue next tile's global loads early (T14)
        const int k0n = (t + 1) * 32;
        unsigned kd = *(const unsigned*)(kgp + (size_t)k0n * 16);
        unsigned vd = *(const unsigned*)(vgp + k0n);

        // compute tile t from buf t&1
        {
            const short* kb = &Kl[t & 1][0][0];
            const short* vb = &Vl[t & 1][0][0];
            bf16x4 K0 = *(const bf16x4*)(kb + lq * KROW + 4 * g);
            bf16x4 K1 = *(const bf16x4*)(kb + (16 + lq) * KROW + 4 * g);
            bf16x4 V0 = *(const bf16x4*)(vb + lq * VROW + 4 * g);
            bf16x4 V1 = *(const bf16x4*)(vb + lq * VROW + 16 + 4 * g);
            const f32x4 zz = {0.f, 0.f, 0.f, 0.f};
            f32x4 s0 = __builtin_amdgcn_mfma_f32_16x16x16bf16_1k(K0, qf, zz, 0, 0, 0);
            f32x4 s1 = __builtin_amdgcn_mfma_f32_16x16x16bf16_1k(K1, qf, zz, 0, 0, 0);
            float p0[4], p1[4];
            #pragma unroll
            for (int r = 0; r < 4; ++r) {
                p0[r] = __builtin_amdgcn_exp2f(s0[r]);
                p1[r] = __builtin_amdgcn_exp2f(s1[r]);
            }
            bf16x4 pt0 = pack4(p0);
            bf16x4 pt1 = pack4(p1);
            o  = __builtin_amdgcn_mfma_f32_16x16x16bf16_1k(V0, pt0, o, 0, 0, 0);
            o  = __builtin_amdgcn_mfma_f32_16x16x16bf16_1k(V1, pt1, o, 0, 0, 0);
            ps = __builtin_amdgcn_mfma_f32_16x16x16bf16_1k(af1, pt0, ps, 0, 0, 0);
            ps = __builtin_amdgcn_mfma_f32_16x16x16bf16_1k(af1, pt1, ps, 0, 0, 0);
        }

        // write next tile into the other buffer, then barrier
        const int nb = (t + 1) & 1;
        *(unsigned*)(kwp + nb * kbufstride) = kd;
        *(unsigned*)(vwp + nb * vbufstride) = vd;
        __syncthreads();
    }

    {   // tail tile 31: local keys 992..999 valid; mask P (g>=2) AND V-frag
        const short* kb = &Kl[1][0][0];
        const short* vb = &Vl[1][0][0];
        bf16x4 K0 = *(const bf16x4*)(kb + lq * KROW + 4 * g);
        bf16x4 V0 = *(const bf16x4*)(vb + lq * VROW + 4 * g);
        if (g >= 2) V0 = (bf16x4){0, 0, 0, 0};
        const f32x4 zz = {0.f, 0.f, 0.f, 0.f};
        f32x4 s0 = __builtin_amdgcn_mfma_f32_16x16x16bf16_1k(K0, qf, zz, 0, 0, 0);
        float p0[4];
        #pragma unroll
        for (int r = 0; r < 4; ++r)
            p0[r] = (g < 2) ? __builtin_amdgcn_exp2f(s0[r]) : 0.f;
        bf16x4 pt0 = pack4(p0);
        o  = __builtin_amdgcn_mfma_f32_16x16x16bf16_1k(V0, pt0, o, 0, 0, 0);
        ps = __builtin_amdgcn_mfma_f32_16x16x16bf16_1k(af1, pt0, ps, 0, 0, 0);
    }

    if (qvalid) {
        const float wz = kbw[z];
        f32x4 ow = {o[0] * wz, o[1] * wz, o[2] * wz, o[3] * wz};
        *(f32x4*)(po + (size_t)z * LL * CC + (size_t)(q0 + lq) * CC + hd0 + 4 * g) = ow;
        if (g == 0) pl[(z * 8 + h) * LL + q0 + lq] = ps[0] * wz;
    }
}

// combine: attb[q][c] = bf16( sum_z po / sum_z pl )
__global__ void attn_combine(const float* __restrict__ po,
                             const float* __restrict__ pl,
                             short* __restrict__ attb) {
    int i = blockIdx.x * blockDim.x + threadIdx.x;
    if (i >= LL * CC / 4) return;
    int q  = i >> 5;
    int c0 = (i & 31) * 4;
    int h  = c0 >> 4;
    size_t off = (size_t)q * CC + c0;
    f32x4 o = {0.f, 0.f, 0.f, 0.f};
    float l = 0.f;
    #pragma unroll
    for (int zz = 0; zz < KSPLIT; ++zz) {
        f32x4 t = *(const f32x4*)(po + (size_t)zz * LL * CC + off);
        o[0] += t[0]; o[1] += t[1]; o[2] += t[2]; o[3] += t[3];
        l += pl[(zz * 8 + h) * LL + q];
    }
    float inv = 1.f / l;
    bf16x4 res = {bf16rne(o[0] * inv), bf16rne(o[1] * inv),
                  bf16rne(o[2] * inv), bf16rne(o[3] * inv)};
    *(bf16x4*)(attb + off) = res;
}

// ---------------------------------------------------------------------------
extern "C" void kernel_launch(void* const* d_in, const int* in_sizes, int n_in,
                              void* d_out, int out_size, void* d_ws, size_t ws_size,
                              hipStream_t stream) {
    const float* z    = (const float*)d_in[0];
    const float* r    = (const float*)d_in[1];
    const float* se   = (const float*)d_in[2];
    const float* Wq   = (const float*)d_in[3];
    const float* Wk   = (const float*)d_in[4];
    const float* Wv   = (const float*)d_in[5];
    const float* Wp   = (const float*)d_in[6];
    const float* beta = (const float*)d_in[7];
    const float* ln1g = (const float*)d_in[8];
    const float* ln1b = (const float*)d_in[9];
    const float* w1   = (const float*)d_in[10];
    const float* b1   = (const float*)d_in[11];
    const float* w2   = (const float*)d_in[12];
    const float* b2   = (const float*)d_in[13];
    const float* ln2g = (const float*)d_in[14];
    const float* ln2b = (const float*)d_in[15];
    float* out = (float*)d_out;

    float* ws   = (float*)d_ws;
    float* tok  = ws;                               // 512000 f
    float* kbw  = tok + LL * CC;                    // 8 f (16B aligned)
    float* pl   = kbw + 8;                          // KSPLIT*8*LL = 128000 f
    float* po   = pl + KSPLIT * 8 * LL;             // KSPLIT*LL*CC f = 8 MB
    short* hdn  = (short*)po;                       // aliased: FFN phase only
    short* tokb = (short*)(po + (size_t)KSPLIT * LL * CC);
    short* attb = tokb + LL * CC;
    short* Qb   = attb + LL * CC;
    short* Kh   = Qb   + LL * CC;                   // head-major [H][L][16] + slack
    short* Vt   = Kh   + LL * CC + 1024;            // transposed [C][L] + slack
    short* wt8  = Vt   + LL * CC + 1024;
    short* w1t  = wt8  + 8 * 16384;
    short* w2t  = w1t  + 65536;

    prep_weights<<<1024, 256, 0, stream>>>(Wq, Wk, Wv, Wp, w1, w2, wt8, w1t, w2t);
    tokenize_kernel<<<2000, 256, 0, stream>>>(z, se, tok, tokb);
    kbw_kernel<<<1, 64, 0, stream>>>(r, beta, kbw);

    for (int l = 0; l < NLAYER; ++l) {
        const short* wqt = wt8 + (size_t)(0 * 2 + l) * 16384;
        const short* wkt = wt8 + (size_t)(1 * 2 + l) * 16384;
        const short* wvt = wt8 + (size_t)(2 * 2 + l) * 16384;
        const short* wpt = wt8 + (size_t)(3 * 2 + l) * 16384;
        mfma_gemm3<<<dim3(LL / 16, 1, 3), 256, 0, stream>>>(
            tokb, wqt, wkt, wvt, Qb, Kh, Vt, LL, CC, CC);
        attn_mfma_kernel<<<dim3((LL / 16 + 3) / 4, 8, KSPLIT), 256, 0, stream>>>(
            Qb, Kh, Vt, kbw + l * KSPLIT, po, pl);
        attn_combine<<<(LL * CC / 4 + 255) / 256, 256, 0, stream>>>(po, pl, attb);
        mfma_gemm_ln<<<LL / 16, 256, 0, stream>>>(
            attb, wpt, nullptr, tok, ln1g + l * CC, ln1b + l * CC,
            tok, tokb, LL, CC);
    }

    mfma_gemm<<<dim3(LL / 16, 4), 256, 0, stream>>>(tokb, w1t, b1, hdn, LL, CC, 4 * CC, 1 | 2);
    mfma_gemm_ln<<<LL / 16, 256, 0, stream>>>(
        hdn, w2t, b2, tok, ln2g, ln2b, tok, tokb, LL, 4 * CC);

    detok_kernel<<<2000, 256, 0, stream>>>(tok, out);
}

// Round 11
// 104.150 us; speedup vs baseline: 3.0183x; 1.1066x over previous
//
#include <hip/hip_runtime.h>
#include <hip/hip_bf16.h>
#include <math.h>

// Problem constants: S=4, B=1, C=128, h=w=d=10 -> N=1000, L=4000, nL=2, H=8, Dh=16
#define LL 4000
#define CC 128
#define NN 1000
#define NLAYER 2
#define KSPLIT 4                        // == S; split-K aligned to sequences
#define SCLOG2 0.36067376022224085f    // 0.25 * log2(e), folded into Q
#define KROW 20                        // padded LDS row (shorts) for K tile [32][KROW]
#define VROW 36                        // padded LDS row (shorts) for V^T tile [16][VROW]

typedef __attribute__((ext_vector_type(4))) short bf16x4;
typedef __attribute__((ext_vector_type(8))) short short8;
typedef __attribute__((ext_vector_type(4))) float f32x4;
typedef __attribute__((ext_vector_type(2))) unsigned int u32x2;

__device__ __forceinline__ short bf16rne(float f) {
    return __builtin_bit_cast(short, __float2bfloat16(f));
}
__device__ __forceinline__ float bf16tof(short s) {
    return __builtin_bit_cast(float, (unsigned)((unsigned short)s) << 16);
}

// pack 4 f32 -> 4 bf16 (truncate) via 2x v_perm_b32
__device__ __forceinline__ bf16x4 pack4(const float* p) {
    unsigned w01 = __builtin_amdgcn_perm(__builtin_bit_cast(unsigned, p[1]),
                                         __builtin_bit_cast(unsigned, p[0]),
                                         0x07060302u);
    unsigned w23 = __builtin_amdgcn_perm(__builtin_bit_cast(unsigned, p[3]),
                                         __builtin_bit_cast(unsigned, p[2]),
                                         0x07060302u);
    u32x2 w = {w01, w23};
    return __builtin_bit_cast(bf16x4, w);
}

// ---------------------------------------------------------------------------
// tokenize via LDS-tiled transpose: z[S,C,N] + se[S,C] -> tok[S*N, C] (+bf16)
__global__ void tokenize_kernel(const float* __restrict__ z,
                                const float* __restrict__ se,
                                float* __restrict__ tok,
                                short* __restrict__ tokb) {
    __shared__ float tl[32][33];
    const int s  = blockIdx.z;
    const int c0 = blockIdx.y * 32;
    const int n0 = blockIdx.x * 32;
    const int tx = threadIdx.x & 31, ty = threadIdx.x >> 5;
    #pragma unroll
    for (int i = 0; i < 4; ++i) {          // read coalesced over n
        int n = n0 + tx;
        if (n < NN) tl[ty * 4 + i][tx] = z[((size_t)s * CC + c0 + ty * 4 + i) * NN + n];
    }
    __syncthreads();
    #pragma unroll
    for (int i = 0; i < 4; ++i) {          // write coalesced over c
        int n = n0 + ty * 4 + i;
        if (n < NN) {
            int c = c0 + tx;
            float v = tl[tx][ty * 4 + i] + se[s * CC + c];
            size_t o = ((size_t)(s * NN + n)) * CC + c;
            tok[o] = v;
            tokb[o] = bf16rne(v);
        }
    }
}

// detokenize via LDS-tiled transpose: tok[S*N, C] -> out[S, C, N]
__global__ void detok_kernel(const float* __restrict__ tok,
                             float* __restrict__ out) {
    __shared__ float tl[32][33];
    const int s  = blockIdx.z;
    const int c0 = blockIdx.y * 32;
    const int n0 = blockIdx.x * 32;
    const int tx = threadIdx.x & 31, ty = threadIdx.x >> 5;
    #pragma unroll
    for (int i = 0; i < 4; ++i) {          // read coalesced over c
        int n = n0 + ty * 4 + i;
        if (n < NN) tl[ty * 4 + i][tx] = tok[((size_t)(s * NN + n)) * CC + c0 + tx];
    }
    __syncthreads();
    #pragma unroll
    for (int i = 0; i < 4; ++i) {          // write coalesced over n
        int n = n0 + tx;
        if (n < NN) out[((size_t)s * CC + c0 + ty * 4 + i) * NN + n] = tl[tx][ty * 4 + i];
    }
}

// ---------------------------------------------------------------------------
// weight prep: bf16 + transpose -> Wt[N][K]; also kbw[l*KSPLIT+z] = r[z]^beta[l]
__global__ void prep_weights(const float* __restrict__ Wq, const float* __restrict__ Wk,
                             const float* __restrict__ Wv, const float* __restrict__ Wp,
                             const float* __restrict__ w1, const float* __restrict__ w2,
                             const float* __restrict__ r, const float* __restrict__ beta,
                             short* __restrict__ wt8, short* __restrict__ w1t,
                             short* __restrict__ w2t, float* __restrict__ kbw) {
    int idx = blockIdx.x * blockDim.x + threadIdx.x;
    if (idx < 8 * 16384) {
        int m = idx >> 14, i = idx & 16383;
        int n = i >> 7, k = i & 127;
        const float* src = (m < 2) ? Wq + (size_t)m * 16384
                         : (m < 4) ? Wk + (size_t)(m - 2) * 16384
                         : (m < 6) ? Wv + (size_t)(m - 4) * 16384
                                   : Wp + (size_t)(m - 6) * 16384;
        wt8[idx] = bf16rne(src[k * 128 + n]);
    } else if (idx < 8 * 16384 + 65536) {
        int i = idx - 8 * 16384;
        int n = i >> 7, k = i & 127;
        w1t[i] = bf16rne(w1[(size_t)k * 512 + n]);
    } else if (idx < 8 * 16384 + 2 * 65536) {
        int i = idx - 8 * 16384 - 65536;
        int n = i >> 9, k = i & 511;
        w2t[i] = bf16rne(w2[(size_t)k * 128 + n]);
    } else if (idx < 8 * 16384 + 2 * 65536 + NLAYER * KSPLIT) {
        int i = idx - (8 * 16384 + 2 * 65536);
        int l = i / KSPLIT, zz = i - l * KSPLIT;
        kbw[i] = exp2f(beta[l] * __log2f(r[zz]));
    }
}

// ---------------------------------------------------------------------------
// MFMA GEMM body: out[M,N] = act(A[M,K] @ Wt[N,K]^T + bias)
// flags: 1 = bf16 out, 2 = exact GELU, 4 = bf16 transposed out [N][M],
//        8 = *SCLOG2, 16 = bf16 head-major out [N/16][M][16]
__device__ __forceinline__ void gemm_body(
        const short* __restrict__ A, const short* __restrict__ Wt,
        const float* __restrict__ bias, void* __restrict__ outp,
        int M, int K, int N, int flags, int row0, int col0) {
    __shared__ short Al[16][136];
    __shared__ short Wl[128][136];
    const int tid = threadIdx.x;
    const int lane = tid & 63;
    const int w = tid >> 6;
    const int lq = lane & 15, g = lane >> 4;

    f32x4 acc[2] = {{0.f,0.f,0.f,0.f},{0.f,0.f,0.f,0.f}};

    for (int kc = 0; kc < K; kc += 128) {
        {
            int r = tid >> 4, c = (tid & 15) * 8;
            *(short8*)&Al[r][c] = *(const short8*)(A + (size_t)(row0 + r) * K + kc + c);
        }
        {
            int c = (tid & 15) * 8;
            int nb = tid >> 4;
            #pragma unroll
            for (int i = 0; i < 8; ++i) {
                int n = nb + i * 16;
                *(short8*)&Wl[n][c] = *(const short8*)(Wt + (size_t)(col0 + n) * K + kc + c);
            }
        }
        __syncthreads();
        bf16x4 af[8];
        #pragma unroll
        for (int ks = 0; ks < 8; ++ks)
            af[ks] = *(const bf16x4*)&Al[lq][ks * 16 + g * 4];
        #pragma unroll
        for (int ct = 0; ct < 2; ++ct) {
            int n = (w * 2 + ct) * 16 + lq;
            #pragma unroll
            for (int ks = 0; ks < 8; ++ks) {
                bf16x4 bfr = *(const bf16x4*)&Wl[n][ks * 16 + g * 4];
                acc[ct] = __builtin_amdgcn_mfma_f32_16x16x16bf16_1k(af[ks], bfr, acc[ct], 0, 0, 0);
            }
        }
        __syncthreads();
    }
    #pragma unroll
    for (int ct = 0; ct < 2; ++ct) {
        int col = col0 + (w * 2 + ct) * 16 + lq;
        float bv = bias ? bias[col] : 0.f;
        float v[4];
        #pragma unroll
        for (int r = 0; r < 4; ++r) {
            v[r] = acc[ct][r] + bv;
            if (flags & 2) v[r] = 0.5f * v[r] * (1.f + erff(v[r] * 0.70710678118654752f));
            if (flags & 8) v[r] *= SCLOG2;
        }
        if (flags & 4) {
            bf16x4 res = {bf16rne(v[0]), bf16rne(v[1]), bf16rne(v[2]), bf16rne(v[3])};
            *(bf16x4*)((short*)outp + (size_t)col * M + row0 + g * 4) = res;
        } else if (flags & 16) {   // head-major [H][M][16]
            #pragma unroll
            for (int r = 0; r < 4; ++r)
                ((short*)outp)[((size_t)(col >> 4) * M + (row0 + g * 4 + r)) * 16 + (col & 15)] = bf16rne(v[r]);
        } else if (flags & 1) {
            #pragma unroll
            for (int r = 0; r < 4; ++r)
                ((short*)outp)[(size_t)(row0 + g * 4 + r) * N + col] = bf16rne(v[r]);
        } else {
            #pragma unroll
            for (int r = 0; r < 4; ++r)
                ((float*)outp)[(size_t)(row0 + g * 4 + r) * N + col] = v[r];
        }
    }
}

__global__ __launch_bounds__(256) void mfma_gemm(
        const short* __restrict__ A, const short* __restrict__ Wt,
        const float* __restrict__ bias, void* __restrict__ outp,
        int M, int K, int N, int flags) {
    gemm_body(A, Wt, bias, outp, M, K, N, flags,
              blockIdx.x * 16, blockIdx.y * 128);
}

// fused QKV: z=0 Q (bf16, *SCLOG2), z=1 K (head-major [H][L][16]), z=2 V^T [C][L]
__global__ __launch_bounds__(256) void mfma_gemm3(
        const short* __restrict__ A,
        const short* __restrict__ W0, const short* __restrict__ W1,
        const short* __restrict__ W2,
        short* __restrict__ o0, short* __restrict__ o1, short* __restrict__ o2,
        int M, int K, int N) {
    const short* Wt = (blockIdx.z == 0) ? W0 : (blockIdx.z == 1) ? W1 : W2;
    short* o = (blockIdx.z == 0) ? o0 : (blockIdx.z == 1) ? o1 : o2;
    int flags = (blockIdx.z == 0) ? (1 | 8) : (blockIdx.z == 1) ? 16 : 4;
    gemm_body(A, Wt, nullptr, o, M, K, N, flags, blockIdx.x * 16, 0);
}

// ---------------------------------------------------------------------------
// Fused MFMA GEMM (N=128) + residual add + LayerNorm. Block = 4 waves =
// 16 full rows; stats via intra-wave shuffles + tiny LDS exchange.
__global__ __launch_bounds__(256) void mfma_gemm_ln(
        const short* __restrict__ A, const short* __restrict__ Wt,
        const float* __restrict__ bias, const float* __restrict__ resid,
        const float* __restrict__ gam, const float* __restrict__ bet,
        float* __restrict__ outf, short* __restrict__ outb,
        int M, int K) {
    __shared__ short Al[16][136];
    __shared__ short Wl[128][136];
    __shared__ float sL[4][4][4], s2L[4][4][4];
    const int tid = threadIdx.x;
    const int lane = tid & 63;
    const int w = tid >> 6;
    const int lq = lane & 15, g = lane >> 4;
    const int row0 = blockIdx.x * 16;

    f32x4 acc[2] = {{0.f,0.f,0.f,0.f},{0.f,0.f,0.f,0.f}};

    for (int kc = 0; kc < K; kc += 128) {
        {
            int r = tid >> 4, c = (tid & 15) * 8;
            *(short8*)&Al[r][c] = *(const short8*)(A + (size_t)(row0 + r) * K + kc + c);
        }
        {
            int c = (tid & 15) * 8;
            int nb = tid >> 4;
            #pragma unroll
            for (int i = 0; i < 8; ++i) {
                int n = nb + i * 16;
                *(short8*)&Wl[n][c] = *(const short8*)(Wt + (size_t)n * K + kc + c);
            }
        }
        __syncthreads();
        bf16x4 af[8];
        #pragma unroll
        for (int ks = 0; ks < 8; ++ks)
            af[ks] = *(const bf16x4*)&Al[lq][ks * 16 + g * 4];
        #pragma unroll
        for (int ct = 0; ct < 2; ++ct) {
            int n = (w * 2 + ct) * 16 + lq;
            #pragma unroll
            for (int ks = 0; ks < 8; ++ks) {
                bf16x4 bfr = *(const bf16x4*)&Wl[n][ks * 16 + g * 4];
                acc[ct] = __builtin_amdgcn_mfma_f32_16x16x16bf16_1k(af[ks], bfr, acc[ct], 0, 0, 0);
            }
        }
        __syncthreads();
    }

    float v[2][4];
    int cols[2] = {(w * 2) * 16 + lq, (w * 2 + 1) * 16 + lq};
    #pragma unroll
    for (int ct = 0; ct < 2; ++ct) {
        float bv = bias ? bias[cols[ct]] : 0.f;
        #pragma unroll
        for (int r = 0; r < 4; ++r)
            v[ct][r] = acc[ct][r] + bv +
                       resid[(size_t)(row0 + g * 4 + r) * CC + cols[ct]];
    }
    float sr[4], s2r[4];
    #pragma unroll
    for (int r = 0; r < 4; ++r) {
        sr[r]  = v[0][r] + v[1][r];
        s2r[r] = v[0][r] * v[0][r] + v[1][r] * v[1][r];
    }
    #pragma unroll
    for (int off = 1; off < 16; off <<= 1) {
        #pragma unroll
        for (int r = 0; r < 4; ++r) {
            sr[r]  += __shfl_xor(sr[r],  off);
            s2r[r] += __shfl_xor(s2r[r], off);
        }
    }
    if (lq == 0) {
        #pragma unroll
        for (int r = 0; r < 4; ++r) { sL[w][g][r] = sr[r]; s2L[w][g][r] = s2r[r]; }
    }
    __syncthreads();
    #pragma unroll
    for (int r = 0; r < 4; ++r) {
        float s = 0.f, s2 = 0.f;
        #pragma unroll
        for (int ww = 0; ww < 4; ++ww) { s += sL[ww][g][r]; s2 += s2L[ww][g][r]; }
        float mu = s * (1.f / CC);
        float var = s2 * (1.f / CC) - mu * mu;
        float rstd = rsqrtf(var + 1e-5f);
        size_t rowoff = (size_t)(row0 + g * 4 + r) * CC;
        #pragma unroll
        for (int ct = 0; ct < 2; ++ct) {
            float y = (v[ct][r] - mu) * rstd * gam[cols[ct]] + bet[cols[ct]];
            outf[rowoff + cols[ct]] = y;
            outb[rowoff + cols[ct]] = bf16rne(y);
        }
    }
}

// ---------------------------------------------------------------------------
// MFMA flash attention (r7 structure, prefetch depth 2): fixed-shift softmax,
// sequence-aligned split-K, LDS-staged 32-key K/V tiles shared by 4 waves.
// Global load for tile t+2 issued at top of iter t; data for tile t+1 (loaded
// last iter) ds-written at end of iter t -> ~2 compute phases of latency slack.
// Partials stored bf16 (wz folded); pl stays f32.
__global__ __launch_bounds__(256) void attn_mfma_kernel(
        const short* __restrict__ Qb, const short* __restrict__ Kh,
        const short* __restrict__ Vt, const float* __restrict__ kbw,
        short* __restrict__ pob, float* __restrict__ pl) {
    __shared__ short Kl[2][32][KROW];
    __shared__ short Vl[2][16][VROW];
    const int tid  = threadIdx.x;
    const int lane = tid & 63;
    const int wv   = tid >> 6;
    const int lq = lane & 15;
    const int g  = lane >> 4;
    const int h  = blockIdx.y;
    const int z  = blockIdx.z;
    const int qt = blockIdx.x * 4 + wv;
    const int q0 = qt * 16;
    const int hd0 = h * 16;
    const int kbase = z * NN;
    const bool qvalid = qt < LL / 16;

    bf16x4 qf = {0, 0, 0, 0};
    if (qvalid) qf = *(const bf16x4*)(Qb + (size_t)(q0 + lq) * CC + hd0 + 4 * g);

    // ones-row A fragment: A[0][k] = 1 -> D[0][q] = sum_k P[k][q]
    const short onev = (lq == 0) ? (short)0x3F80 : (short)0;
    const bf16x4 af1 = {onev, onev, onev, onev};

    // staging addresses (thread-flat across the block)
    const short* kgp = Kh + ((size_t)h * LL + kbase) * 16 + tid * 2;
    const short* vgp = Vt + (size_t)(hd0 + (tid >> 4)) * LL + kbase + (tid & 15) * 2;
    short* kwp = &Kl[0][0][0] + (tid >> 3) * KROW + (tid & 7) * 2;
    short* vwp = &Vl[0][0][0] + (tid >> 4) * VROW + (tid & 15) * 2;
    const int kbufstride = 32 * KROW;
    const int vbufstride = 16 * VROW;

    f32x4 o  = {0.f, 0.f, 0.f, 0.f};
    f32x4 ps = {0.f, 0.f, 0.f, 0.f};

    {   // prologue: stage tile 0 into buf 0; issue tile 1 loads
        unsigned kd = *(const unsigned*)kgp;
        unsigned vd = *(const unsigned*)vgp;
        *(unsigned*)kwp = kd;
        *(unsigned*)vwp = vd;
    }
    unsigned kdA = *(const unsigned*)(kgp + (size_t)32 * 16);
    unsigned vdA = *(const unsigned*)(vgp + 32);
    __syncthreads();

    for (int t = 0; t < 31; ++t) {
        // issue tile t+2's loads (2 phases ahead)
        unsigned kdB, vdB;
        if (t < 30) {
            kdB = *(const unsigned*)(kgp + (size_t)(t + 2) * 32 * 16);
            vdB = *(const unsigned*)(vgp + (t + 2) * 32);
        }

        // compute tile t from buf t&1
        {
            const short* kb = &Kl[t & 1][0][0];
            const short* vb = &Vl[t & 1][0][0];
            bf16x4 K0 = *(const bf16x4*)(kb + lq * KROW + 4 * g);
            bf16x4 K1 = *(const bf16x4*)(kb + (16 + lq) * KROW + 4 * g);
            bf16x4 V0 = *(const bf16x4*)(vb + lq * VROW + 4 * g);
            bf16x4 V1 = *(const bf16x4*)(vb + lq * VROW + 16 + 4 * g);
            const f32x4 zz = {0.f, 0.f, 0.f, 0.f};
            f32x4 s0 = __builtin_amdgcn_mfma_f32_16x16x16bf16_1k(K0, qf, zz, 0, 0, 0);
            f32x4 s1 = __builtin_amdgcn_mfma_f32_16x16x16bf16_1k(K1, qf, zz, 0, 0, 0);
            float p0[4], p1[4];
            #pragma unroll
            for (int r = 0; r < 4; ++r) {
                p0[r] = __builtin_amdgcn_exp2f(s0[r]);
                p1[r] = __builtin_amdgcn_exp2f(s1[r]);
            }
            bf16x4 pt0 = pack4(p0);
            bf16x4 pt1 = pack4(p1);
            o  = __builtin_amdgcn_mfma_f32_16x16x16bf16_1k(V0, pt0, o, 0, 0, 0);
            o  = __builtin_amdgcn_mfma_f32_16x16x16bf16_1k(V1, pt1, o, 0, 0, 0);
            ps = __builtin_amdgcn_mfma_f32_16x16x16bf16_1k(af1, pt0, ps, 0, 0, 0);
            ps = __builtin_amdgcn_mfma_f32_16x16x16bf16_1k(af1, pt1, ps, 0, 0, 0);
        }

        // write tile t+1's data (loaded last iter) into the other buffer
        const int nb = (t + 1) & 1;
        *(unsigned*)(kwp + nb * kbufstride) = kdA;
        *(unsigned*)(vwp + nb * vbufstride) = vdA;
        __syncthreads();
        if (t < 30) { kdA = kdB; vdA = vdB; }
    }

    {   // tail tile 31: local keys 992..999 valid; mask P (g>=2) AND V-frag
        const short* kb = &Kl[1][0][0];
        const short* vb = &Vl[1][0][0];
        bf16x4 K0 = *(const bf16x4*)(kb + lq * KROW + 4 * g);
        bf16x4 V0 = *(const bf16x4*)(vb + lq * VROW + 4 * g);
        if (g >= 2) V0 = (bf16x4){0, 0, 0, 0};
        const f32x4 zz = {0.f, 0.f, 0.f, 0.f};
        f32x4 s0 = __builtin_amdgcn_mfma_f32_16x16x16bf16_1k(K0, qf, zz, 0, 0, 0);
        float p0[4];
        #pragma unroll
        for (int r = 0; r < 4; ++r)
            p0[r] = (g < 2) ? __builtin_amdgcn_exp2f(s0[r]) : 0.f;
        bf16x4 pt0 = pack4(p0);
        o  = __builtin_amdgcn_mfma_f32_16x16x16bf16_1k(V0, pt0, o, 0, 0, 0);
        ps = __builtin_amdgcn_mfma_f32_16x16x16bf16_1k(af1, pt0, ps, 0, 0, 0);
    }

    if (qvalid) {
        const float wz = kbw[z];
        bf16x4 ow = {bf16rne(o[0] * wz), bf16rne(o[1] * wz),
                     bf16rne(o[2] * wz), bf16rne(o[3] * wz)};
        *(bf16x4*)(pob + (size_t)z * LL * CC + (size_t)(q0 + lq) * CC + hd0 + 4 * g) = ow;
        if (g == 0) pl[(z * 8 + h) * LL + q0 + lq] = ps[0] * wz;
    }
}

// combine: attb[q][c] = bf16( sum_z pob / sum_z pl )
__global__ void attn_combine(const short* __restrict__ pob,
                             const float* __restrict__ pl,
                             short* __restrict__ attb) {
    int i = blockIdx.x * blockDim.x + threadIdx.x;
    if (i >= LL * CC / 4) return;
    int q  = i >> 5;
    int c0 = (i & 31) * 4;
    int h  = c0 >> 4;
    size_t off = (size_t)q * CC + c0;
    float o0 = 0.f, o1 = 0.f, o2 = 0.f, o3 = 0.f;
    float l = 0.f;
    #pragma unroll
    for (int zz = 0; zz < KSPLIT; ++zz) {
        bf16x4 t = *(const bf16x4*)(pob + (size_t)zz * LL * CC + off);
        o0 += bf16tof(t[0]); o1 += bf16tof(t[1]);
        o2 += bf16tof(t[2]); o3 += bf16tof(t[3]);
        l += pl[(zz * 8 + h) * LL + q];
    }
    float inv = 1.f / l;
    bf16x4 res = {bf16rne(o0 * inv), bf16rne(o1 * inv),
                  bf16rne(o2 * inv), bf16rne(o3 * inv)};
    *(bf16x4*)(attb + off) = res;
}

// ---------------------------------------------------------------------------
extern "C" void kernel_launch(void* const* d_in, const int* in_sizes, int n_in,
                              void* d_out, int out_size, void* d_ws, size_t ws_size,
                              hipStream_t stream) {
    const float* z    = (const float*)d_in[0];
    const float* r    = (const float*)d_in[1];
    const float* se   = (const float*)d_in[2];
    const float* Wq   = (const float*)d_in[3];
    const float* Wk   = (const float*)d_in[4];
    const float* Wv   = (const float*)d_in[5];
    const float* Wp   = (const float*)d_in[6];
    const float* beta = (const float*)d_in[7];
    const float* ln1g = (const float*)d_in[8];
    const float* ln1b = (const float*)d_in[9];
    const float* w1   = (const float*)d_in[10];
    const float* b1   = (const float*)d_in[11];
    const float* w2   = (const float*)d_in[12];
    const float* b2   = (const float*)d_in[13];
    const float* ln2g = (const float*)d_in[14];
    const float* ln2b = (const float*)d_in[15];
    float* out = (float*)d_out;

    float* ws   = (float*)d_ws;
    float* tok  = ws;                               // 512000 f
    float* kbw  = tok + LL * CC;                    // 8 f (16B aligned)
    float* pl   = kbw + 8;                          // KSPLIT*8*LL = 128000 f
    short* pob  = (short*)(pl + KSPLIT * 8 * LL);   // KSPLIT*LL*CC sh = 4 MB
    short* hdn  = pob;                              // aliased: FFN phase only
    short* tokb = pob + (size_t)KSPLIT * LL * CC;
    short* attb = tokb + LL * CC;
    short* Qb   = attb + LL * CC;
    short* Kh   = Qb   + LL * CC;                   // head-major [H][L][16] + slack
    short* Vt   = Kh   + LL * CC + 1024;            // transposed [C][L] + slack
    short* wt8  = Vt   + LL * CC + 1024;
    short* w1t  = wt8  + 8 * 16384;
    short* w2t  = w1t  + 65536;

    prep_weights<<<1025, 256, 0, stream>>>(Wq, Wk, Wv, Wp, w1, w2, r, beta,
                                           wt8, w1t, w2t, kbw);
    tokenize_kernel<<<dim3(32, 4, 4), 256, 0, stream>>>(z, se, tok, tokb);

    for (int l = 0; l < NLAYER; ++l) {
        const short* wqt = wt8 + (size_t)(0 * 2 + l) * 16384;
        const short* wkt = wt8 + (size_t)(1 * 2 + l) * 16384;
        const short* wvt = wt8 + (size_t)(2 * 2 + l) * 16384;
        const short* wpt = wt8 + (size_t)(3 * 2 + l) * 16384;
        mfma_gemm3<<<dim3(LL / 16, 1, 3), 256, 0, stream>>>(
            tokb, wqt, wkt, wvt, Qb, Kh, Vt, LL, CC, CC);
        attn_mfma_kernel<<<dim3((LL / 16 + 3) / 4, 8, KSPLIT), 256, 0, stream>>>(
            Qb, Kh, Vt, kbw + l * KSPLIT, pob, pl);
        attn_combine<<<(LL * CC / 4 + 255) / 256, 256, 0, stream>>>(pob, pl, attb);
        mfma_gemm_ln<<<LL / 16, 256, 0, stream>>>(
            attb, wpt, nullptr, tok, ln1g + l * CC, ln1b + l * CC,
            tok, tokb, LL, CC);
    }

    mfma_gemm<<<dim3(LL / 16, 4), 256, 0, stream>>>(tokb, w1t, b1, hdn, LL, CC, 4 * CC, 1 | 2);
    mfma_gemm_ln<<<LL / 16, 256, 0, stream>>>(
        hdn, w2t, b2, tok, ln2g, ln2b, tok, tokb, LL, 4 * CC);

    detok_kernel<<<dim3(32, 4, 4), 256, 0, stream>>>(tok, out);
}

// Round 12
// 100.164 us; speedup vs baseline: 3.1384x; 1.0398x over previous
//
#include <hip/hip_runtime.h>
#include <hip/hip_bf16.h>
#include <math.h>

// Problem constants: S=4, B=1, C=128, h=w=d=10 -> N=1000, L=4000, nL=2, H=8, Dh=16
#define LL 4000
#define CC 128
#define NN 1000
#define NLAYER 2
#define KSPLIT 4                        // == S; split-K aligned to sequences
#define SCLOG2 0.36067376022224085f    // 0.25 * log2(e), folded into Q
#define KROW 20                        // padded LDS row (shorts) for K tile [32][KROW]
#define VROW 36                        // padded LDS row (shorts) for V^T tile [16][VROW]

typedef __attribute__((ext_vector_type(4))) short bf16x4;
typedef __attribute__((ext_vector_type(8))) short short8;
typedef __attribute__((ext_vector_type(4))) float f32x4;
typedef __attribute__((ext_vector_type(2))) unsigned int u32x2;

__device__ __forceinline__ short bf16rne(float f) {
    return __builtin_bit_cast(short, __float2bfloat16(f));
}
__device__ __forceinline__ float bf16tof(short s) {
    return __builtin_bit_cast(float, (unsigned)((unsigned short)s) << 16);
}

// pack 4 f32 -> 4 bf16 (truncate) via 2x v_perm_b32
__device__ __forceinline__ bf16x4 pack4(const float* p) {
    unsigned w01 = __builtin_amdgcn_perm(__builtin_bit_cast(unsigned, p[1]),
                                         __builtin_bit_cast(unsigned, p[0]),
                                         0x07060302u);
    unsigned w23 = __builtin_amdgcn_perm(__builtin_bit_cast(unsigned, p[3]),
                                         __builtin_bit_cast(unsigned, p[2]),
                                         0x07060302u);
    u32x2 w = {w01, w23};
    return __builtin_bit_cast(bf16x4, w);
}

// ---------------------------------------------------------------------------
// tokenize via LDS-tiled transpose: z[S,C,N] + se[S,C] -> tok[S*N, C] (+bf16)
__global__ void tokenize_kernel(const float* __restrict__ z,
                                const float* __restrict__ se,
                                float* __restrict__ tok,
                                short* __restrict__ tokb) {
    __shared__ float tl[32][33];
    const int s  = blockIdx.z;
    const int c0 = blockIdx.y * 32;
    const int n0 = blockIdx.x * 32;
    const int tx = threadIdx.x & 31, ty = threadIdx.x >> 5;
    #pragma unroll
    for (int i = 0; i < 4; ++i) {          // read coalesced over n
        int n = n0 + tx;
        if (n < NN) tl[ty * 4 + i][tx] = z[((size_t)s * CC + c0 + ty * 4 + i) * NN + n];
    }
    __syncthreads();
    #pragma unroll
    for (int i = 0; i < 4; ++i) {          // write coalesced over c
        int n = n0 + ty * 4 + i;
        if (n < NN) {
            int c = c0 + tx;
            float v = tl[tx][ty * 4 + i] + se[s * CC + c];
            size_t o = ((size_t)(s * NN + n)) * CC + c;
            tok[o] = v;
            tokb[o] = bf16rne(v);
        }
    }
}

// detokenize via LDS-tiled transpose: tok[S*N, C] -> out[S, C, N]
__global__ void detok_kernel(const float* __restrict__ tok,
                             float* __restrict__ out) {
    __shared__ float tl[32][33];
    const int s  = blockIdx.z;
    const int c0 = blockIdx.y * 32;
    const int n0 = blockIdx.x * 32;
    const int tx = threadIdx.x & 31, ty = threadIdx.x >> 5;
    #pragma unroll
    for (int i = 0; i < 4; ++i) {          // read coalesced over c
        int n = n0 + ty * 4 + i;
        if (n < NN) tl[ty * 4 + i][tx] = tok[((size_t)(s * NN + n)) * CC + c0 + tx];
    }
    __syncthreads();
    #pragma unroll
    for (int i = 0; i < 4; ++i) {          // write coalesced over n
        int n = n0 + tx;
        if (n < NN) out[((size_t)s * CC + c0 + ty * 4 + i) * NN + n] = tl[tx][ty * 4 + i];
    }
}

// ---------------------------------------------------------------------------
// weight prep: bf16 + transpose -> Wt[N][K]; also kbw[l*KSPLIT+z] = r[z]^beta[l]
__global__ void prep_weights(const float* __restrict__ Wq, const float* __restrict__ Wk,
                             const float* __restrict__ Wv, const float* __restrict__ Wp,
                             const float* __restrict__ w1, const float* __restrict__ w2,
                             const float* __restrict__ r, const float* __restrict__ beta,
                             short* __restrict__ wt8, short* __restrict__ w1t,
                             short* __restrict__ w2t, float* __restrict__ kbw) {
    int idx = blockIdx.x * blockDim.x + threadIdx.x;
    if (idx < 8 * 16384) {
        int m = idx >> 14, i = idx & 16383;
        int n = i >> 7, k = i & 127;
        const float* src = (m < 2) ? Wq + (size_t)m * 16384
                         : (m < 4) ? Wk + (size_t)(m - 2) * 16384
                         : (m < 6) ? Wv + (size_t)(m - 4) * 16384
                                   : Wp + (size_t)(m - 6) * 16384;
        wt8[idx] = bf16rne(src[k * 128 + n]);
    } else if (idx < 8 * 16384 + 65536) {
        int i = idx - 8 * 16384;
        int n = i >> 7, k = i & 127;
        w1t[i] = bf16rne(w1[(size_t)k * 512 + n]);
    } else if (idx < 8 * 16384 + 2 * 65536) {
        int i = idx - 8 * 16384 - 65536;
        int n = i >> 9, k = i & 511;
        w2t[i] = bf16rne(w2[(size_t)k * 128 + n]);
    } else if (idx < 8 * 16384 + 2 * 65536 + NLAYER * KSPLIT) {
        int i = idx - (8 * 16384 + 2 * 65536);
        int l = i / KSPLIT, zz = i - l * KSPLIT;
        kbw[i] = exp2f(beta[l] * __log2f(r[zz]));
    }
}

// ---------------------------------------------------------------------------
// MFMA GEMM body: out[M,N] = act(A[M,K] @ Wt[N,K]^T + bias)
// flags: 1 = bf16 out, 2 = exact GELU, 4 = bf16 transposed out [N][M],
//        8 = *SCLOG2, 16 = bf16 head-major out [N/16][M][16]
__device__ __forceinline__ void gemm_body(
        const short* __restrict__ A, const short* __restrict__ Wt,
        const float* __restrict__ bias, void* __restrict__ outp,
        int M, int K, int N, int flags, int row0, int col0) {
    __shared__ short Al[16][136];
    __shared__ short Wl[128][136];
    const int tid = threadIdx.x;
    const int lane = tid & 63;
    const int w = tid >> 6;
    const int lq = lane & 15, g = lane >> 4;

    f32x4 acc[2] = {{0.f,0.f,0.f,0.f},{0.f,0.f,0.f,0.f}};

    for (int kc = 0; kc < K; kc += 128) {
        {
            int r = tid >> 4, c = (tid & 15) * 8;
            *(short8*)&Al[r][c] = *(const short8*)(A + (size_t)(row0 + r) * K + kc + c);
        }
        {
            int c = (tid & 15) * 8;
            int nb = tid >> 4;
            #pragma unroll
            for (int i = 0; i < 8; ++i) {
                int n = nb + i * 16;
                *(short8*)&Wl[n][c] = *(const short8*)(Wt + (size_t)(col0 + n) * K + kc + c);
            }
        }
        __syncthreads();
        bf16x4 af[8];
        #pragma unroll
        for (int ks = 0; ks < 8; ++ks)
            af[ks] = *(const bf16x4*)&Al[lq][ks * 16 + g * 4];
        #pragma unroll
        for (int ct = 0; ct < 2; ++ct) {
            int n = (w * 2 + ct) * 16 + lq;
            #pragma unroll
            for (int ks = 0; ks < 8; ++ks) {
                bf16x4 bfr = *(const bf16x4*)&Wl[n][ks * 16 + g * 4];
                acc[ct] = __builtin_amdgcn_mfma_f32_16x16x16bf16_1k(af[ks], bfr, acc[ct], 0, 0, 0);
            }
        }
        __syncthreads();
    }
    #pragma unroll
    for (int ct = 0; ct < 2; ++ct) {
        int col = col0 + (w * 2 + ct) * 16 + lq;
        float bv = bias ? bias[col] : 0.f;
        float v[4];
        #pragma unroll
        for (int r = 0; r < 4; ++r) {
            v[r] = acc[ct][r] + bv;
            if (flags & 2) v[r] = 0.5f * v[r] * (1.f + erff(v[r] * 0.70710678118654752f));
            if (flags & 8) v[r] *= SCLOG2;
        }
        if (flags & 4) {
            bf16x4 res = {bf16rne(v[0]), bf16rne(v[1]), bf16rne(v[2]), bf16rne(v[3])};
            *(bf16x4*)((short*)outp + (size_t)col * M + row0 + g * 4) = res;
        } else if (flags & 16) {   // head-major [H][M][16]
            #pragma unroll
            for (int r = 0; r < 4; ++r)
                ((short*)outp)[((size_t)(col >> 4) * M + (row0 + g * 4 + r)) * 16 + (col & 15)] = bf16rne(v[r]);
        } else if (flags & 1) {
            #pragma unroll
            for (int r = 0; r < 4; ++r)
                ((short*)outp)[(size_t)(row0 + g * 4 + r) * N + col] = bf16rne(v[r]);
        } else {
            #pragma unroll
            for (int r = 0; r < 4; ++r)
                ((float*)outp)[(size_t)(row0 + g * 4 + r) * N + col] = v[r];
        }
    }
}

__global__ __launch_bounds__(256) void mfma_gemm(
        const short* __restrict__ A, const short* __restrict__ Wt,
        const float* __restrict__ bias, void* __restrict__ outp,
        int M, int K, int N, int flags) {
    gemm_body(A, Wt, bias, outp, M, K, N, flags,
              blockIdx.x * 16, blockIdx.y * 128);
}

// fused QKV: z=0 Q (bf16, *SCLOG2), z=1 K (head-major [H][L][16]), z=2 V^T [C][L]
__global__ __launch_bounds__(256) void mfma_gemm3(
        const short* __restrict__ A,
        const short* __restrict__ W0, const short* __restrict__ W1,
        const short* __restrict__ W2,
        short* __restrict__ o0, short* __restrict__ o1, short* __restrict__ o2,
        int M, int K, int N) {
    const short* Wt = (blockIdx.z == 0) ? W0 : (blockIdx.z == 1) ? W1 : W2;
    short* o = (blockIdx.z == 0) ? o0 : (blockIdx.z == 1) ? o1 : o2;
    int flags = (blockIdx.z == 0) ? (1 | 8) : (blockIdx.z == 1) ? 16 : 4;
    gemm_body(A, Wt, nullptr, o, M, K, N, flags, blockIdx.x * 16, 0);
}

// ---------------------------------------------------------------------------
// Fused MFMA GEMM (N=128) + residual add + LayerNorm. Block = 4 waves =
// 16 full rows; stats via intra-wave shuffles + tiny LDS exchange.
__global__ __launch_bounds__(256) void mfma_gemm_ln(
        const short* __restrict__ A, const short* __restrict__ Wt,
        const float* __restrict__ bias, const float* __restrict__ resid,
        const float* __restrict__ gam, const float* __restrict__ bet,
        float* __restrict__ outf, short* __restrict__ outb,
        int M, int K) {
    __shared__ short Al[16][136];
    __shared__ short Wl[128][136];
    __shared__ float sL[4][4][4], s2L[4][4][4];
    const int tid = threadIdx.x;
    const int lane = tid & 63;
    const int w = tid >> 6;
    const int lq = lane & 15, g = lane >> 4;
    const int row0 = blockIdx.x * 16;

    f32x4 acc[2] = {{0.f,0.f,0.f,0.f},{0.f,0.f,0.f,0.f}};

    for (int kc = 0; kc < K; kc += 128) {
        {
            int r = tid >> 4, c = (tid & 15) * 8;
            *(short8*)&Al[r][c] = *(const short8*)(A + (size_t)(row0 + r) * K + kc + c);
        }
        {
            int c = (tid & 15) * 8;
            int nb = tid >> 4;
            #pragma unroll
            for (int i = 0; i < 8; ++i) {
                int n = nb + i * 16;
                *(short8*)&Wl[n][c] = *(const short8*)(Wt + (size_t)n * K + kc + c);
            }
        }
        __syncthreads();
        bf16x4 af[8];
        #pragma unroll
        for (int ks = 0; ks < 8; ++ks)
            af[ks] = *(const bf16x4*)&Al[lq][ks * 16 + g * 4];
        #pragma unroll
        for (int ct = 0; ct < 2; ++ct) {
            int n = (w * 2 + ct) * 16 + lq;
            #pragma unroll
            for (int ks = 0; ks < 8; ++ks) {
                bf16x4 bfr = *(const bf16x4*)&Wl[n][ks * 16 + g * 4];
                acc[ct] = __builtin_amdgcn_mfma_f32_16x16x16bf16_1k(af[ks], bfr, acc[ct], 0, 0, 0);
            }
        }
        __syncthreads();
    }

    float v[2][4];
    int cols[2] = {(w * 2) * 16 + lq, (w * 2 + 1) * 16 + lq};
    #pragma unroll
    for (int ct = 0; ct < 2; ++ct) {
        float bv = bias ? bias[cols[ct]] : 0.f;
        #pragma unroll
        for (int r = 0; r < 4; ++r)
            v[ct][r] = acc[ct][r] + bv +
                       resid[(size_t)(row0 + g * 4 + r) * CC + cols[ct]];
    }
    float sr[4], s2r[4];
    #pragma unroll
    for (int r = 0; r < 4; ++r) {
        sr[r]  = v[0][r] + v[1][r];
        s2r[r] = v[0][r] * v[0][r] + v[1][r] * v[1][r];
    }
    #pragma unroll
    for (int off = 1; off < 16; off <<= 1) {
        #pragma unroll
        for (int r = 0; r < 4; ++r) {
            sr[r]  += __shfl_xor(sr[r],  off);
            s2r[r] += __shfl_xor(s2r[r], off);
        }
    }
    if (lq == 0) {
        #pragma unroll
        for (int r = 0; r < 4; ++r) { sL[w][g][r] = sr[r]; s2L[w][g][r] = s2r[r]; }
    }
    __syncthreads();
    #pragma unroll
    for (int r = 0; r < 4; ++r) {
        float s = 0.f, s2 = 0.f;
        #pragma unroll
        for (int ww = 0; ww < 4; ++ww) { s += sL[ww][g][r]; s2 += s2L[ww][g][r]; }
        float mu = s * (1.f / CC);
        float var = s2 * (1.f / CC) - mu * mu;
        float rstd = rsqrtf(var + 1e-5f);
        size_t rowoff = (size_t)(row0 + g * 4 + r) * CC;
        #pragma unroll
        for (int ct = 0; ct < 2; ++ct) {
            float y = (v[ct][r] - mu) * rstd * gam[cols[ct]] + bet[cols[ct]];
            outf[rowoff + cols[ct]] = y;
            outb[rowoff + cols[ct]] = bf16rne(y);
        }
    }
}

// ---------------------------------------------------------------------------
// Proj-GEMM + LN with INLINE split-K combine: A-tile = (sum_z pob)/(sum_z pl),
// computed during the A-stage (K=128, single k-step). Numerically identical
// to the standalone attn_combine + gemm_ln path.
__global__ __launch_bounds__(256) void mfma_gemm_ln_cmb(
        const short* __restrict__ pob, const float* __restrict__ pl,
        const short* __restrict__ Wt, const float* __restrict__ resid,
        const float* __restrict__ gam, const float* __restrict__ bet,
        float* __restrict__ outf, short* __restrict__ outb) {
    __shared__ short Al[16][136];
    __shared__ short Wl[128][136];
    __shared__ float sL[4][4][4], s2L[4][4][4];
    const int tid = threadIdx.x;
    const int lane = tid & 63;
    const int w = tid >> 6;
    const int lq = lane & 15, g = lane >> 4;
    const int row0 = blockIdx.x * 16;

    {   // A-stage with inline combine: thread -> row r, col chunk c0..c0+7
        int r = tid >> 4, c0 = (tid & 15) * 8;
        int row = row0 + r;
        int h = c0 >> 4;
        float a8[8] = {0.f,0.f,0.f,0.f,0.f,0.f,0.f,0.f};
        float den = 0.f;
        #pragma unroll
        for (int zz = 0; zz < KSPLIT; ++zz) {
            short8 t = *(const short8*)(pob + (size_t)zz * LL * CC + (size_t)row * CC + c0);
            #pragma unroll
            for (int j = 0; j < 8; ++j) a8[j] += bf16tof(t[j]);
            den += pl[(zz * 8 + h) * LL + row];
        }
        float inv = 1.f / den;
        short8 packed;
        #pragma unroll
        for (int j = 0; j < 8; ++j) packed[j] = bf16rne(a8[j] * inv);
        *(short8*)&Al[r][c0] = packed;
    }
    {   // W-stage (K=128)
        int c = (tid & 15) * 8;
        int nb = tid >> 4;
        #pragma unroll
        for (int i = 0; i < 8; ++i) {
            int n = nb + i * 16;
            *(short8*)&Wl[n][c] = *(const short8*)(Wt + (size_t)n * CC + c);
        }
    }
    __syncthreads();

    f32x4 acc[2] = {{0.f,0.f,0.f,0.f},{0.f,0.f,0.f,0.f}};
    bf16x4 af[8];
    #pragma unroll
    for (int ks = 0; ks < 8; ++ks)
        af[ks] = *(const bf16x4*)&Al[lq][ks * 16 + g * 4];
    #pragma unroll
    for (int ct = 0; ct < 2; ++ct) {
        int n = (w * 2 + ct) * 16 + lq;
        #pragma unroll
        for (int ks = 0; ks < 8; ++ks) {
            bf16x4 bfr = *(const bf16x4*)&Wl[n][ks * 16 + g * 4];
            acc[ct] = __builtin_amdgcn_mfma_f32_16x16x16bf16_1k(af[ks], bfr, acc[ct], 0, 0, 0);
        }
    }

    float v[2][4];
    int cols[2] = {(w * 2) * 16 + lq, (w * 2 + 1) * 16 + lq};
    #pragma unroll
    for (int ct = 0; ct < 2; ++ct) {
        #pragma unroll
        for (int r = 0; r < 4; ++r)
            v[ct][r] = acc[ct][r] +
                       resid[(size_t)(row0 + g * 4 + r) * CC + cols[ct]];
    }
    float sr[4], s2r[4];
    #pragma unroll
    for (int r = 0; r < 4; ++r) {
        sr[r]  = v[0][r] + v[1][r];
        s2r[r] = v[0][r] * v[0][r] + v[1][r] * v[1][r];
    }
    #pragma unroll
    for (int off = 1; off < 16; off <<= 1) {
        #pragma unroll
        for (int r = 0; r < 4; ++r) {
            sr[r]  += __shfl_xor(sr[r],  off);
            s2r[r] += __shfl_xor(s2r[r], off);
        }
    }
    if (lq == 0) {
        #pragma unroll
        for (int r = 0; r < 4; ++r) { sL[w][g][r] = sr[r]; s2L[w][g][r] = s2r[r]; }
    }
    __syncthreads();
    #pragma unroll
    for (int r = 0; r < 4; ++r) {
        float s = 0.f, s2 = 0.f;
        #pragma unroll
        for (int ww = 0; ww < 4; ++ww) { s += sL[ww][g][r]; s2 += s2L[ww][g][r]; }
        float mu = s * (1.f / CC);
        float var = s2 * (1.f / CC) - mu * mu;
        float rstd = rsqrtf(var + 1e-5f);
        size_t rowoff = (size_t)(row0 + g * 4 + r) * CC;
        #pragma unroll
        for (int ct = 0; ct < 2; ++ct) {
            float y = (v[ct][r] - mu) * rstd * gam[cols[ct]] + bet[cols[ct]];
            outf[rowoff + cols[ct]] = y;
            outb[rowoff + cols[ct]] = bf16rne(y);
        }
    }
}

// ---------------------------------------------------------------------------
// MFMA flash attention (r7 staging + depth-2 prefetch, 2 q-tiles per wave):
// fixed-shift softmax, sequence-aligned split-K. Each wave computes 32 queries
// against the shared K/V LDS tiles -> per-query staging/LDS traffic halves.
__global__ __launch_bounds__(256) void attn_mfma_kernel(
        const short* __restrict__ Qb, const short* __restrict__ Kh,
        const short* __restrict__ Vt, const float* __restrict__ kbw,
        short* __restrict__ pob, float* __restrict__ pl) {
    __shared__ short Kl[2][32][KROW];
    __shared__ short Vl[2][16][VROW];
    const int tid  = threadIdx.x;
    const int lane = tid & 63;
    const int wv   = tid >> 6;
    const int lq = lane & 15;
    const int g  = lane >> 4;
    const int h  = blockIdx.y;
    const int z  = blockIdx.z;
    const int qtA = blockIdx.x * 8 + wv * 2;
    const int qtB = qtA + 1;
    const bool qvA = qtA < LL / 16;
    const bool qvB = qtB < LL / 16;
    const int hd0 = h * 16;
    const int kbase = z * NN;

    bf16x4 qfA = {0, 0, 0, 0}, qfB = {0, 0, 0, 0};
    if (qvA) qfA = *(const bf16x4*)(Qb + (size_t)(qtA * 16 + lq) * CC + hd0 + 4 * g);
    if (qvB) qfB = *(const bf16x4*)(Qb + (size_t)(qtB * 16 + lq) * CC + hd0 + 4 * g);

    // ones-row A fragment: A[0][k] = 1 -> D[0][q] = sum_k P[k][q]
    const short onev = (lq == 0) ? (short)0x3F80 : (short)0;
    const bf16x4 af1 = {onev, onev, onev, onev};

    // staging addresses (thread-flat across the block)
    const short* kgp = Kh + ((size_t)h * LL + kbase) * 16 + tid * 2;
    const short* vgp = Vt + (size_t)(hd0 + (tid >> 4)) * LL + kbase + (tid & 15) * 2;
    short* kwp = &Kl[0][0][0] + (tid >> 3) * KROW + (tid & 7) * 2;
    short* vwp = &Vl[0][0][0] + (tid >> 4) * VROW + (tid & 15) * 2;
    const int kbufstride = 32 * KROW;
    const int vbufstride = 16 * VROW;

    f32x4 oA  = {0.f, 0.f, 0.f, 0.f}, oB  = {0.f, 0.f, 0.f, 0.f};
    f32x4 psA = {0.f, 0.f, 0.f, 0.f}, psB = {0.f, 0.f, 0.f, 0.f};

    {   // prologue: stage tile 0 into buf 0; issue tile 1 loads
        unsigned kd = *(const unsigned*)kgp;
        unsigned vd = *(const unsigned*)vgp;
        *(unsigned*)kwp = kd;
        *(unsigned*)vwp = vd;
    }
    unsigned kdA = *(const unsigned*)(kgp + (size_t)32 * 16);
    unsigned vdA = *(const unsigned*)(vgp + 32);
    __syncthreads();

    for (int t = 0; t < 31; ++t) {
        // issue tile t+2's loads (2 phases ahead)
        unsigned kdB, vdB;
        if (t < 30) {
            kdB = *(const unsigned*)(kgp + (size_t)(t + 2) * 32 * 16);
            vdB = *(const unsigned*)(vgp + (t + 2) * 32);
        }

        // compute tile t from buf t&1 for BOTH q-tiles
        {
            const short* kb = &Kl[t & 1][0][0];
            const short* vb = &Vl[t & 1][0][0];
            bf16x4 K0 = *(const bf16x4*)(kb + lq * KROW + 4 * g);
            bf16x4 K1 = *(const bf16x4*)(kb + (16 + lq) * KROW + 4 * g);
            bf16x4 V0 = *(const bf16x4*)(vb + lq * VROW + 4 * g);
            bf16x4 V1 = *(const bf16x4*)(vb + lq * VROW + 16 + 4 * g);
            const f32x4 zz = {0.f, 0.f, 0.f, 0.f};
            f32x4 sA0 = __builtin_amdgcn_mfma_f32_16x16x16bf16_1k(K0, qfA, zz, 0, 0, 0);
            f32x4 sA1 = __builtin_amdgcn_mfma_f32_16x16x16bf16_1k(K1, qfA, zz, 0, 0, 0);
            f32x4 sB0 = __builtin_amdgcn_mfma_f32_16x16x16bf16_1k(K0, qfB, zz, 0, 0, 0);
            f32x4 sB1 = __builtin_amdgcn_mfma_f32_16x16x16bf16_1k(K1, qfB, zz, 0, 0, 0);
            float pA0[4], pA1[4], pB0[4], pB1[4];
            #pragma unroll
            for (int r = 0; r < 4; ++r) {
                pA0[r] = __builtin_amdgcn_exp2f(sA0[r]);
                pA1[r] = __builtin_amdgcn_exp2f(sA1[r]);
                pB0[r] = __builtin_amdgcn_exp2f(sB0[r]);
                pB1[r] = __builtin_amdgcn_exp2f(sB1[r]);
            }
            bf16x4 ptA0 = pack4(pA0), ptA1 = pack4(pA1);
            bf16x4 ptB0 = pack4(pB0), ptB1 = pack4(pB1);
            oA  = __builtin_amdgcn_mfma_f32_16x16x16bf16_1k(V0, ptA0, oA, 0, 0, 0);
            oA  = __builtin_amdgcn_mfma_f32_16x16x16bf16_1k(V1, ptA1, oA, 0, 0, 0);
            oB  = __builtin_amdgcn_mfma_f32_16x16x16bf16_1k(V0, ptB0, oB, 0, 0, 0);
            oB  = __builtin_amdgcn_mfma_f32_16x16x16bf16_1k(V1, ptB1, oB, 0, 0, 0);
            psA = __builtin_amdgcn_mfma_f32_16x16x16bf16_1k(af1, ptA0, psA, 0, 0, 0);
            psA = __builtin_amdgcn_mfma_f32_16x16x16bf16_1k(af1, ptA1, psA, 0, 0, 0);
            psB = __builtin_amdgcn_mfma_f32_16x16x16bf16_1k(af1, ptB0, psB, 0, 0, 0);
            psB = __builtin_amdgcn_mfma_f32_16x16x16bf16_1k(af1, ptB1, psB, 0, 0, 0);
        }

        // write tile t+1's data (loaded last iter) into the other buffer
        const int nb = (t + 1) & 1;
        *(unsigned*)(kwp + nb * kbufstride) = kdA;
        *(unsigned*)(vwp + nb * vbufstride) = vdA;
        __syncthreads();
        if (t < 30) { kdA = kdB; vdA = vdB; }
    }

    {   // tail tile 31: local keys 992..999 valid; mask P (g>=2) AND V-frag
        const short* kb = &Kl[1][0][0];
        const short* vb = &Vl[1][0][0];
        bf16x4 K0 = *(const bf16x4*)(kb + lq * KROW + 4 * g);
        bf16x4 V0 = *(const bf16x4*)(vb + lq * VROW + 4 * g);
        if (g >= 2) V0 = (bf16x4){0, 0, 0, 0};
        const f32x4 zz = {0.f, 0.f, 0.f, 0.f};
        f32x4 sA0 = __builtin_amdgcn_mfma_f32_16x16x16bf16_1k(K0, qfA, zz, 0, 0, 0);
        f32x4 sB0 = __builtin_amdgcn_mfma_f32_16x16x16bf16_1k(K0, qfB, zz, 0, 0, 0);
        float pA0[4], pB0[4];
        #pragma unroll
        for (int r = 0; r < 4; ++r) {
            pA0[r] = (g < 2) ? __builtin_amdgcn_exp2f(sA0[r]) : 0.f;
            pB0[r] = (g < 2) ? __builtin_amdgcn_exp2f(sB0[r]) : 0.f;
        }
        bf16x4 ptA0 = pack4(pA0), ptB0 = pack4(pB0);
        oA  = __builtin_amdgcn_mfma_f32_16x16x16bf16_1k(V0, ptA0, oA, 0, 0, 0);
        oB  = __builtin_amdgcn_mfma_f32_16x16x16bf16_1k(V0, ptB0, oB, 0, 0, 0);
        psA = __builtin_amdgcn_mfma_f32_16x16x16bf16_1k(af1, ptA0, psA, 0, 0, 0);
        psB = __builtin_amdgcn_mfma_f32_16x16x16bf16_1k(af1, ptB0, psB, 0, 0, 0);
    }

    const float wz = kbw[z];
    if (qvA) {
        bf16x4 ow = {bf16rne(oA[0] * wz), bf16rne(oA[1] * wz),
                     bf16rne(oA[2] * wz), bf16rne(oA[3] * wz)};
        *(bf16x4*)(pob + (size_t)z * LL * CC + (size_t)(qtA * 16 + lq) * CC + hd0 + 4 * g) = ow;
        if (g == 0) pl[(z * 8 + h) * LL + qtA * 16 + lq] = psA[0] * wz;
    }
    if (qvB) {
        bf16x4 ow = {bf16rne(oB[0] * wz), bf16rne(oB[1] * wz),
                     bf16rne(oB[2] * wz), bf16rne(oB[3] * wz)};
        *(bf16x4*)(pob + (size_t)z * LL * CC + (size_t)(qtB * 16 + lq) * CC + hd0 + 4 * g) = ow;
        if (g == 0) pl[(z * 8 + h) * LL + qtB * 16 + lq] = psB[0] * wz;
    }
}

// ---------------------------------------------------------------------------
extern "C" void kernel_launch(void* const* d_in, const int* in_sizes, int n_in,
                              void* d_out, int out_size, void* d_ws, size_t ws_size,
                              hipStream_t stream) {
    const float* z    = (const float*)d_in[0];
    const float* r    = (const float*)d_in[1];
    const float* se   = (const float*)d_in[2];
    const float* Wq   = (const float*)d_in[3];
    const float* Wk   = (const float*)d_in[4];
    const float* Wv   = (const float*)d_in[5];
    const float* Wp   = (const float*)d_in[6];
    const float* beta = (const float*)d_in[7];
    const float* ln1g = (const float*)d_in[8];
    const float* ln1b = (const float*)d_in[9];
    const float* w1   = (const float*)d_in[10];
    const float* b1   = (const float*)d_in[11];
    const float* w2   = (const float*)d_in[12];
    const float* b2   = (const float*)d_in[13];
    const float* ln2g = (const float*)d_in[14];
    const float* ln2b = (const float*)d_in[15];
    float* out = (float*)d_out;

    float* ws   = (float*)d_ws;
    float* tok  = ws;                               // 512000 f
    float* kbw  = tok + LL * CC;                    // 8 f (16B aligned)
    float* pl   = kbw + 8;                          // KSPLIT*8*LL = 128000 f
    short* pob  = (short*)(pl + KSPLIT * 8 * LL);   // KSPLIT*LL*CC sh = 4 MB
    short* hdn  = pob;                              // aliased: FFN phase only
    short* tokb = pob + (size_t)KSPLIT * LL * CC;
    short* Qb   = tokb + LL * CC;
    short* Kh   = Qb   + LL * CC;                   // head-major [H][L][16] + slack
    short* Vt   = Kh   + LL * CC + 1024;            // transposed [C][L] + slack
    short* wt8  = Vt   + LL * CC + 1024;
    short* w1t  = wt8  + 8 * 16384;
    short* w2t  = w1t  + 65536;

    prep_weights<<<1025, 256, 0, stream>>>(Wq, Wk, Wv, Wp, w1, w2, r, beta,
                                           wt8, w1t, w2t, kbw);
    tokenize_kernel<<<dim3(32, 4, 4), 256, 0, stream>>>(z, se, tok, tokb);

    for (int l = 0; l < NLAYER; ++l) {
        const short* wqt = wt8 + (size_t)(0 * 2 + l) * 16384;
        const short* wkt = wt8 + (size_t)(1 * 2 + l) * 16384;
        const short* wvt = wt8 + (size_t)(2 * 2 + l) * 16384;
        const short* wpt = wt8 + (size_t)(3 * 2 + l) * 16384;
        mfma_gemm3<<<dim3(LL / 16, 1, 3), 256, 0, stream>>>(
            tokb, wqt, wkt, wvt, Qb, Kh, Vt, LL, CC, CC);
        attn_mfma_kernel<<<dim3((LL / 16 + 7) / 8, 8, KSPLIT), 256, 0, stream>>>(
            Qb, Kh, Vt, kbw + l * KSPLIT, pob, pl);
        mfma_gemm_ln_cmb<<<LL / 16, 256, 0, stream>>>(
            pob, pl, wpt, tok, ln1g + l * CC, ln1b + l * CC, tok, tokb);
    }

    mfma_gemm<<<dim3(LL / 16, 4), 256, 0, stream>>>(tokb, w1t, b1, hdn, LL, CC, 4 * CC, 1 | 2);
    mfma_gemm_ln<<<LL / 16, 256, 0, stream>>>(
        hdn, w2t, b2, tok, ln2g, ln2b, tok, tokb, LL, 4 * CC);

    detok_kernel<<<dim3(32, 4, 4), 256, 0, stream>>>(tok, out);
}